// Round 1
// baseline (244.638 us; speedup 1.0000x reference)
//
#include <hip/hip_runtime.h>
#include <math.h>

// ProbSparse attention (Informer). B=2 L=4096 H=8 D=64, U_part=u=45.
// Pipeline: k_idx (threefry randint replication) -> k_scoreM (sampled QK -> M)
// -> k_topk (45 extract-max, jax.lax.top_k semantics) -> k_attn (flash-decoding
// partials per 256-key chunk) -> k_merge (exact softmax merge).
// JAX_PARTITIONABLE=1 replicates jax_threefry_partitionable=True (JAX >= 0.5
// default). Flip to 0 if absmax ~0.1 (index-stream mismatch signature).
#define JAX_PARTITIONABLE 1

constexpr int Bc = 2, Lc = 4096, Hc = 8, Dc = 64;
constexpr int BHc = Bc * Hc;     // 16
constexpr int Uc = 45;           // top-k queries
constexpr int NSc = 45;          // samples per query
constexpr int NCHUNK = 16, CHUNK = 256;

struct TF2 { unsigned a, b; };

__host__ __device__ constexpr unsigned rotl32(unsigned v, int n) {
  return (v << n) | (v >> (32 - n));
}

// Threefry-2x32, 20 rounds (JAX reference schedule).
__host__ __device__ constexpr TF2 tf2(unsigned k0, unsigned k1, unsigned x0, unsigned x1) {
  unsigned ks2 = k0 ^ k1 ^ 0x1BD11BDAu;
  x0 += k0; x1 += k1;
  x0 += x1; x1 = rotl32(x1, 13); x1 ^= x0;
  x0 += x1; x1 = rotl32(x1, 15); x1 ^= x0;
  x0 += x1; x1 = rotl32(x1, 26); x1 ^= x0;
  x0 += x1; x1 = rotl32(x1, 6);  x1 ^= x0;
  x0 += k1; x1 += ks2 + 1u;
  x0 += x1; x1 = rotl32(x1, 17); x1 ^= x0;
  x0 += x1; x1 = rotl32(x1, 29); x1 ^= x0;
  x0 += x1; x1 = rotl32(x1, 16); x1 ^= x0;
  x0 += x1; x1 = rotl32(x1, 24); x1 ^= x0;
  x0 += ks2; x1 += k0 + 2u;
  x0 += x1; x1 = rotl32(x1, 13); x1 ^= x0;
  x0 += x1; x1 = rotl32(x1, 15); x1 ^= x0;
  x0 += x1; x1 = rotl32(x1, 26); x1 ^= x0;
  x0 += x1; x1 = rotl32(x1, 6);  x1 ^= x0;
  x0 += k0; x1 += k1 + 3u;
  x0 += x1; x1 = rotl32(x1, 17); x1 ^= x0;
  x0 += x1; x1 = rotl32(x1, 29); x1 ^= x0;
  x0 += x1; x1 = rotl32(x1, 16); x1 ^= x0;
  x0 += x1; x1 = rotl32(x1, 24); x1 ^= x0;
  x0 += k1; x1 += ks2 + 4u;
  x0 += x1; x1 = rotl32(x1, 13); x1 ^= x0;
  x0 += x1; x1 = rotl32(x1, 15); x1 ^= x0;
  x0 += x1; x1 = rotl32(x1, 26); x1 ^= x0;
  x0 += x1; x1 = rotl32(x1, 6);  x1 ^= x0;
  x0 += ks2; x1 += k0 + 5u;
  return TF2{x0, x1};
}

// idx[q][s] = randint(split(key(1))[1]) & 4095. span=4096 | 2^16 => only
// lower_bits stream matters.
__global__ __launch_bounds__(256) void k_idx(int* __restrict__ idx) {
  int f = blockIdx.x * 256 + threadIdx.x;
#if JAX_PARTITIONABLE
  constexpr TF2 kb = tf2(0u, 1u, 0u, 1u);          // 2nd foldlike subkey of key(1)
  TF2 r = tf2(kb.a, kb.b, 0u, (unsigned)f);
  idx[f] = (int)((r.a ^ r.b) & 4095u);
#else
  constexpr TF2 t02 = tf2(0u, 1u, 0u, 2u);
  constexpr TF2 t13 = tf2(0u, 1u, 1u, 3u);         // old split: k2 = (t02.b, t13.b)
  TF2 r = tf2(t02.b, t13.b, (unsigned)f, (unsigned)(f + 92160));
  idx[f] = (int)(r.a & 4095u);
  idx[f + 92160] = (int)(r.b & 4095u);
#endif
}

// M[bh][q] = max_s dot(Q[q],K[idx[q][s]]) - sum_s(...)/4096.
// 16 lanes per q (lane = d-quad), butterfly-sum over 16 lanes.
__global__ __launch_bounds__(256) void k_scoreM(const float* __restrict__ Q, const float* __restrict__ K,
                                                const int* __restrict__ idx, float* __restrict__ M) {
  int tid = threadIdx.x;
  int lane16 = tid & 15;
  int qloc = tid >> 4;
  int bx = blockIdx.x;
  int bh = bx >> 8;
  int q = ((bx & 255) << 4) + qloc;
  int b = bh >> 3, h = bh & 7;
  const float4* Q4 = (const float4*)Q;
  const float4* K4 = (const float4*)K;
  float4 qr = Q4[((b * Lc + q) * Hc + h) * 16 + lane16];
  int kbase = (b * Lc * Hc + h) * 16 + lane16;
  const int* ip = idx + q * NSc;
  float mx = -INFINITY, sm = 0.f;
  #pragma unroll 5
  for (int s = 0; s < NSc; ++s) {
    int kk = ip[s];
    float4 kv = K4[kbase + kk * (Hc * 16)];
    float p = qr.x * kv.x + qr.y * kv.y + qr.z * kv.z + qr.w * kv.w;
    p += __shfl_xor(p, 1);
    p += __shfl_xor(p, 2);
    p += __shfl_xor(p, 4);
    p += __shfl_xor(p, 8);
    mx = fmaxf(mx, p);
    sm += p;
  }
  if (lane16 == 0) M[bh * Lc + q] = mx - sm * (1.0f / Lc);
}

// jax.lax.top_k over 4096 per (b,h): iterative extract-max, ties -> lower index.
__global__ __launch_bounds__(256) void k_topk(const float* __restrict__ M, int* __restrict__ topk) {
  int bh = blockIdx.x;
  int tid = threadIdx.x;
  int w = tid >> 6, lane = tid & 63;
  const float* m = M + bh * Lc;
  float vals[16];
  #pragma unroll
  for (int j = 0; j < 16; ++j) vals[j] = m[j * 256 + tid];
  __shared__ float swv[2][4];
  __shared__ int swi[2][4];
  for (int it = 0; it < Uc; ++it) {
    int pb = it & 1;
    float bv = -INFINITY; int bi = 0x7fffffff;
    #pragma unroll
    for (int j = 0; j < 16; ++j) {
      float v = vals[j];
      int qi = j * 256 + tid;
      if (v > bv) { bv = v; bi = qi; }   // ascending qi scan => first on tie
    }
    #pragma unroll
    for (int off = 1; off < 64; off <<= 1) {
      float ov = __shfl_xor(bv, off);
      int oi = __shfl_xor(bi, off);
      if (ov > bv || (ov == bv && oi < bi)) { bv = ov; bi = oi; }
    }
    if (lane == 0) { swv[pb][w] = bv; swi[pb][w] = bi; }
    __syncthreads();
    float wv = swv[pb][0]; int wi = swi[pb][0];
    #pragma unroll
    for (int c = 1; c < 4; ++c) {
      float cv = swv[pb][c]; int ci = swi[pb][c];
      if (cv > wv || (cv == wv && ci < wi)) { wv = cv; wi = ci; }
    }
    if (tid == 0) topk[bh * Uc + it] = wi;
    #pragma unroll
    for (int j = 0; j < 16; ++j)
      if (j * 256 + tid == wi) vals[j] = -INFINITY;
  }
}

// Flash-decoding partials: one block per (bh, 256-key chunk).
// Phase 1: thread-per-key scores vs 45 staged Q rows; phase 2: per-row local
// softmax (m,l); phase 3: PV with (t,d)-distributed accumulators.
__global__ __launch_bounds__(256) void k_attn(const float* __restrict__ Q, const float* __restrict__ K,
                                              const float* __restrict__ V, const int* __restrict__ amask,
                                              const int* __restrict__ topk,
                                              float* __restrict__ pO, float* __restrict__ pM,
                                              float* __restrict__ pL) {
  int chunk = blockIdx.x, bh = blockIdx.y;
  int b = bh >> 3, h = bh & 7;
  int tid = threadIdx.x;
  __shared__ int tk[Uc];
  __shared__ __align__(16) float qs[Uc * 64];
  __shared__ float sc[48][257];            // +1 pad: PV 4-way t-read -> <=2-way bank alias (free)
  if (tid < Uc) tk[tid] = topk[bh * Uc + tid];
  __syncthreads();
  for (int e = tid; e < Uc * 64; e += 256) {
    int t = e >> 6, d = e & 63;
    qs[e] = Q[((b * Lc + tk[t]) * Hc + h) * Dc + d];
  }
  __syncthreads();
  {
    int k = tid;
    int key = chunk * CHUNK + k;
    const float4* K4 = (const float4*)K;
    int kb = ((b * Lc + key) * Hc + h) * 16;
    float4 kr[16];
    #pragma unroll
    for (int j = 0; j < 16; ++j) kr[j] = K4[kb + j];
    int mk = amask[b * Lc + key];
    const float4* qs4 = (const float4*)qs;
    for (int t = 0; t < Uc; ++t) {
      float acc = 0.f;
      #pragma unroll
      for (int j = 0; j < 16; ++j) {
        float4 qv = qs4[t * 16 + j];
        acc += qv.x * kr[j].x;
        acc += qv.y * kr[j].y;
        acc += qv.z * kr[j].z;
        acc += qv.w * kr[j].w;
      }
      sc[t][k] = mk ? acc * 0.125f : -INFINITY;
    }
    sc[45][k] = 0.f; sc[46][k] = 0.f; sc[47][k] = 0.f;   // zero pad rows for unguarded PV reads
  }
  __syncthreads();
  {
    int w = tid >> 6, lane = tid & 63;
    for (int t = w; t < Uc; t += 4) {
      float x0 = sc[t][lane], x1 = sc[t][lane + 64], x2 = sc[t][lane + 128], x3 = sc[t][lane + 192];
      float ml = fmaxf(fmaxf(x0, x1), fmaxf(x2, x3));
      #pragma unroll
      for (int off = 1; off < 64; off <<= 1) ml = fmaxf(ml, __shfl_xor(ml, off));
      float p0 = 0.f, p1 = 0.f, p2 = 0.f, p3 = 0.f;
      if (ml != -INFINITY) {               // fully-masked chunk guard (avoid exp(nan))
        p0 = __expf(x0 - ml); p1 = __expf(x1 - ml);
        p2 = __expf(x2 - ml); p3 = __expf(x3 - ml);
      }
      sc[t][lane] = p0; sc[t][lane + 64] = p1; sc[t][lane + 128] = p2; sc[t][lane + 192] = p3;
      float ls = p0 + p1 + p2 + p3;
      #pragma unroll
      for (int off = 1; off < 64; off <<= 1) ls += __shfl_xor(ls, off);
      if (lane == 0) {
        pM[(bh * NCHUNK + chunk) * Uc + t] = ml;
        pL[(bh * NCHUNK + chunk) * Uc + t] = ls;
      }
    }
  }
  __syncthreads();
  {
    int ty = tid >> 4, tx = tid & 15;      // t in {ty, ty+16, ty+32}, d = 4*tx..4*tx+3
    float4 o0 = {0.f, 0.f, 0.f, 0.f};
    float4 o1 = {0.f, 0.f, 0.f, 0.f};
    float4 o2 = {0.f, 0.f, 0.f, 0.f};
    const float4* V4 = (const float4*)V;
    int vbase = (b * Lc + chunk * CHUNK) * (Hc * 16) + h * 16 + tx;
    #pragma unroll 4
    for (int k = 0; k < CHUNK; ++k) {
      float4 v4 = V4[vbase + k * (Hc * 16)];
      float p0 = sc[ty][k], p1 = sc[ty + 16][k], p2 = sc[ty + 32][k];
      o0.x += p0 * v4.x; o0.y += p0 * v4.y; o0.z += p0 * v4.z; o0.w += p0 * v4.w;
      o1.x += p1 * v4.x; o1.y += p1 * v4.y; o1.z += p1 * v4.z; o1.w += p1 * v4.w;
      o2.x += p2 * v4.x; o2.y += p2 * v4.y; o2.z += p2 * v4.z; o2.w += p2 * v4.w;
    }
    float4* pO4 = (float4*)pO;
    int obase = ((bh * NCHUNK + chunk) * Uc) * 16 + tx;
    pO4[obase + ty * 16] = o0;
    pO4[obase + (ty + 16) * 16] = o1;
    if (ty < 13) pO4[obase + (ty + 32) * 16] = o2;
  }
}

// Exact merge of chunk partials; out[b][t][h][d].
__global__ __launch_bounds__(256) void k_merge(const float* __restrict__ pO, const float* __restrict__ pM,
                                               const float* __restrict__ pL, float* __restrict__ out) {
  int f = blockIdx.x * 256 + threadIdx.x;   // 180*256 == 46080 exactly
  int d = f & 63, h = (f >> 6) & 7;
  int bt = f >> 9;
  int t = bt % Uc, b = bt / Uc;
  int bh = b * 8 + h;
  float m = -INFINITY;
  #pragma unroll
  for (int c = 0; c < NCHUNK; ++c) m = fmaxf(m, pM[(bh * NCHUNK + c) * Uc + t]);
  float den = 0.f, num = 0.f;
  #pragma unroll
  for (int c = 0; c < NCHUNK; ++c) {
    float mc = pM[(bh * NCHUNK + c) * Uc + t];
    float wgt = (mc == -INFINITY) ? 0.f : __expf(mc - m);
    den += wgt * pL[(bh * NCHUNK + c) * Uc + t];
    num += wgt * pO[((bh * NCHUNK + c) * Uc + t) * 64 + d];
  }
  out[f] = num / den;
}

extern "C" void kernel_launch(void* const* d_in, const int* in_sizes, int n_in,
                              void* d_out, int out_size, void* d_ws, size_t ws_size,
                              hipStream_t stream) {
  const float* Q = (const float*)d_in[0];
  const float* K = (const float*)d_in[1];
  const float* V = (const float*)d_in[2];
  const int* amask = (const int*)d_in[3];
  float* out = (float*)d_out;
  char* ws = (char*)d_ws;
  // ws layout (~4 MB total), fully rewritten every call:
  int*   idx  = (int*)(ws + 0);            // 184320 ints  (737,280 B)
  float* M    = (float*)(ws + 0x0C0000);   // 65536 floats (262,144 B)
  int*   topk = (int*)(ws + 0x100000);     // 720 ints
  float* pM   = (float*)(ws + 0x101000);   // 16*16*45 floats
  float* pL   = (float*)(ws + 0x110000);   // 16*16*45 floats
  float* pO   = (float*)(ws + 0x120000);   // 16*16*45*64 floats (2.95 MB)

#if JAX_PARTITIONABLE
  k_idx<<<720, 256, 0, stream>>>(idx);
#else
  k_idx<<<360, 256, 0, stream>>>(idx);
#endif
  k_scoreM<<<4096, 256, 0, stream>>>(Q, K, idx, M);
  k_topk<<<BHc, 256, 0, stream>>>(M, topk);
  k_attn<<<dim3(NCHUNK, BHc), 256, 0, stream>>>(Q, K, V, amask, topk, pO, pM, pL);
  k_merge<<<180, 256, 0, stream>>>(pO, pM, pL, out);
}

// Round 2
// 244.457 us; speedup vs baseline: 1.0007x; 1.0007x over previous
//
#include <hip/hip_runtime.h>
#include <math.h>

// ProbSparse attention (Informer). B=2 L=4096 H=8 D=64, U_part=u=45.
// R1: k_attn NCHUNK 16->64 (occupancy 10%->~50%), k_scoreM shuffle-free
// (LDS transpose, stride-17 pad), k_topk two-stage wave-only extract-max.
#define JAX_PARTITIONABLE 1

constexpr int Bc = 2, Lc = 4096, Hc = 8, Dc = 64;
constexpr int BHc = Bc * Hc;     // 16
constexpr int Uc = 45;           // top-k queries
constexpr int NSc = 45;          // samples per query

struct TF2 { unsigned a, b; };

__host__ __device__ constexpr unsigned rotl32(unsigned v, int n) {
  return (v << n) | (v >> (32 - n));
}

// Threefry-2x32, 20 rounds (JAX reference schedule).
__host__ __device__ constexpr TF2 tf2(unsigned k0, unsigned k1, unsigned x0, unsigned x1) {
  unsigned ks2 = k0 ^ k1 ^ 0x1BD11BDAu;
  x0 += k0; x1 += k1;
  x0 += x1; x1 = rotl32(x1, 13); x1 ^= x0;
  x0 += x1; x1 = rotl32(x1, 15); x1 ^= x0;
  x0 += x1; x1 = rotl32(x1, 26); x1 ^= x0;
  x0 += x1; x1 = rotl32(x1, 6);  x1 ^= x0;
  x0 += k1; x1 += ks2 + 1u;
  x0 += x1; x1 = rotl32(x1, 17); x1 ^= x0;
  x0 += x1; x1 = rotl32(x1, 29); x1 ^= x0;
  x0 += x1; x1 = rotl32(x1, 16); x1 ^= x0;
  x0 += x1; x1 = rotl32(x1, 24); x1 ^= x0;
  x0 += ks2; x1 += k0 + 2u;
  x0 += x1; x1 = rotl32(x1, 13); x1 ^= x0;
  x0 += x1; x1 = rotl32(x1, 15); x1 ^= x0;
  x0 += x1; x1 = rotl32(x1, 26); x1 ^= x0;
  x0 += x1; x1 = rotl32(x1, 6);  x1 ^= x0;
  x0 += k0; x1 += k1 + 3u;
  x0 += x1; x1 = rotl32(x1, 17); x1 ^= x0;
  x0 += x1; x1 = rotl32(x1, 29); x1 ^= x0;
  x0 += x1; x1 = rotl32(x1, 16); x1 ^= x0;
  x0 += x1; x1 = rotl32(x1, 24); x1 ^= x0;
  x0 += k1; x1 += ks2 + 4u;
  x0 += x1; x1 = rotl32(x1, 13); x1 ^= x0;
  x0 += x1; x1 = rotl32(x1, 15); x1 ^= x0;
  x0 += x1; x1 = rotl32(x1, 26); x1 ^= x0;
  x0 += x1; x1 = rotl32(x1, 6);  x1 ^= x0;
  x0 += ks2; x1 += k0 + 5u;
  return TF2{x0, x1};
}

__global__ __launch_bounds__(256) void k_idx(int* __restrict__ idx) {
  int f = blockIdx.x * 256 + threadIdx.x;
  constexpr TF2 kb = tf2(0u, 1u, 0u, 1u);
  TF2 r = tf2(kb.a, kb.b, 0u, (unsigned)f);
  idx[f] = (int)((r.a ^ r.b) & 4095u);
}

// M[bh][q] = max_s dot(Q[q],K[idx[q][s]]) - sum_s(...)/4096.
// Shuffle-free: per-lane partials -> LDS (stride 17: avoids measured 32-way
// conflict on the transpose read) -> 720-pair sum -> per-q max/mean.
__global__ __launch_bounds__(256) void k_scoreM(const float* __restrict__ Q, const float* __restrict__ K,
                                                const int* __restrict__ idx, float* __restrict__ M) {
  __shared__ float sc2[720 * 17];   // [ (qloc*45+s) * 17 + lane16 ]
  __shared__ float ps[720];         // [qloc*45+s]
  int tid = threadIdx.x;
  int lane16 = tid & 15;
  int qloc = tid >> 4;
  int bx = blockIdx.x;
  int bh = bx >> 8;
  int q = ((bx & 255) << 4) + qloc;
  int b = bh >> 3, h = bh & 7;
  const float4* Q4 = (const float4*)Q;
  const float4* K4 = (const float4*)K;
  float4 qr = Q4[((b * Lc + q) * Hc + h) * 16 + lane16];
  int kbase = (b * Lc * Hc + h) * 16 + lane16;
  const int* ip = idx + q * NSc;
  float* myrow = sc2 + (qloc * NSc) * 17 + lane16;
  #pragma unroll 9
  for (int s = 0; s < NSc; ++s) {
    int kk = ip[s];
    float4 kv = K4[kbase + kk * (Hc * 16)];
    myrow[s * 17] = qr.x * kv.x + qr.y * kv.y + qr.z * kv.z + qr.w * kv.w;
  }
  __syncthreads();
  for (int p = tid; p < 720; p += 256) {
    const float* r = sc2 + p * 17;
    float s0 = 0.f;
    #pragma unroll
    for (int j = 0; j < 16; ++j) s0 += r[j];
    ps[p] = s0;
  }
  __syncthreads();
  if (tid < 16) {
    const float* r = ps + tid * NSc;
    float mx = r[0], sm = r[0];
    for (int s = 1; s < NSc; ++s) { float v = r[s]; mx = fmaxf(mx, v); sm += v; }
    M[bh * Lc + ((bx & 255) << 4) + tid] = mx - sm * (1.0f / Lc);
  }
}

// top_k stage 1: one wave per (bh, 512-seg): local top-45, sorted, no barriers.
__global__ __launch_bounds__(64) void k_topk1(const float* __restrict__ M,
                                              float* __restrict__ cv, int* __restrict__ ci) {
  int seg = blockIdx.x, bh = blockIdx.y;
  int lane = threadIdx.x;
  const float* m = M + bh * Lc + seg * 512;
  float v[8];
  #pragma unroll
  for (int j = 0; j < 8; ++j) v[j] = m[j * 64 + lane];
  int base = seg * 512;
  int obase = (bh * 8 + seg) * Uc;
  for (int it = 0; it < Uc; ++it) {
    float bv = v[0]; int bj = 0;
    #pragma unroll
    for (int j = 1; j < 8; ++j) if (v[j] > bv) { bv = v[j]; bj = j; }  // strict >: earliest j (lowest idx) on tie
    int bi = base + bj * 64 + lane;
    #pragma unroll
    for (int off = 1; off < 64; off <<= 1) {
      float ov = __shfl_xor(bv, off);
      int oi = __shfl_xor(bi, off);
      if (ov > bv || (ov == bv && oi < bi)) { bv = ov; bi = oi; }
    }
    if (((bi - base) & 63) == lane) v[(bi - base) >> 6] = -INFINITY;
    if (lane == 0) { cv[obase + it] = bv; ci[obase + it] = bi; }
  }
}

// top_k stage 2: one wave per bh merges 8x45=360 candidates -> global top-45.
__global__ __launch_bounds__(64) void k_topk2(const float* __restrict__ cv, const int* __restrict__ ci,
                                              int* __restrict__ topk) {
  int bh = blockIdx.x;
  int lane = threadIdx.x;
  float v[6]; int id[6];
  #pragma unroll
  for (int j = 0; j < 6; ++j) {
    int p = j * 64 + lane;
    bool ok = p < 8 * Uc;
    v[j] = ok ? cv[bh * 8 * Uc + p] : -INFINITY;
    id[j] = ok ? ci[bh * 8 * Uc + p] : 0x7fffffff;
  }
  for (int it = 0; it < Uc; ++it) {
    float bv = v[0]; int bi = id[0];
    #pragma unroll
    for (int j = 1; j < 6; ++j)
      if (v[j] > bv || (v[j] == bv && id[j] < bi)) { bv = v[j]; bi = id[j]; }
    #pragma unroll
    for (int off = 1; off < 64; off <<= 1) {
      float ov = __shfl_xor(bv, off);
      int oi = __shfl_xor(bi, off);
      if (ov > bv || (ov == bv && oi < bi)) { bv = ov; bi = oi; }
    }
    #pragma unroll
    for (int j = 0; j < 6; ++j) if (id[j] == bi) v[j] = -INFINITY;
    if (lane == 0) topk[bh * Uc + it] = bi;
  }
}

// Flash-decoding partials: one block per (bh, CH-key chunk), CH = 4096/NC.
template<int NC>
__global__ __launch_bounds__(256) void k_attn(const float* __restrict__ Q, const float* __restrict__ K,
                                              const float* __restrict__ V, const int* __restrict__ amask,
                                              const int* __restrict__ topk,
                                              float* __restrict__ pO, float* __restrict__ pM,
                                              float* __restrict__ pL) {
  constexpr int CH = Lc / NC;
  constexpr int TG = 256 / CH;
  int chunk = blockIdx.x, bh = blockIdx.y;
  int b = bh >> 3, h = bh & 7;
  int tid = threadIdx.x;
  __shared__ int tk[Uc];
  __shared__ __align__(16) float qs[Uc * 64];
  __shared__ float sc[48][CH + 1];
  if (tid < Uc) tk[tid] = topk[bh * Uc + tid];
  __syncthreads();
  for (int e = tid; e < Uc * 64; e += 256) {
    int t = e >> 6, d = e & 63;
    qs[e] = Q[((b * Lc + tk[t]) * Hc + h) * Dc + d];
  }
  for (int e = tid; e < 3 * CH; e += 256) sc[45 + e / CH][e % CH] = 0.f;
  __syncthreads();
  {
    int k = tid % CH, tg = tid / CH;
    int key = chunk * CH + k;
    const float4* K4 = (const float4*)K;
    int kb = ((b * Lc + key) * Hc + h) * 16;
    float4 kr[16];
    #pragma unroll
    for (int j = 0; j < 16; ++j) kr[j] = K4[kb + j];
    int mk = amask[b * Lc + key];
    const float4* qs4 = (const float4*)qs;
    for (int t = tg; t < Uc; t += TG) {
      float acc = 0.f;
      #pragma unroll
      for (int j = 0; j < 16; ++j) {
        float4 qv = qs4[t * 16 + j];
        acc += qv.x * kr[j].x;
        acc += qv.y * kr[j].y;
        acc += qv.z * kr[j].z;
        acc += qv.w * kr[j].w;
      }
      sc[t][k] = mk ? acc * 0.125f : -INFINITY;
    }
  }
  __syncthreads();
  {
    constexpr int COLS = CH / 64;
    int w = tid >> 6, lane = tid & 63;
    for (int t = w; t < Uc; t += 4) {
      float x[COLS];
      float ml = -INFINITY;
      #pragma unroll
      for (int c = 0; c < COLS; ++c) { x[c] = sc[t][c * 64 + lane]; ml = fmaxf(ml, x[c]); }
      #pragma unroll
      for (int off = 1; off < 64; off <<= 1) ml = fmaxf(ml, __shfl_xor(ml, off));
      float ls = 0.f;
      if (ml != -INFINITY) {
        #pragma unroll
        for (int c = 0; c < COLS; ++c) { x[c] = __expf(x[c] - ml); ls += x[c]; }
      } else {
        #pragma unroll
        for (int c = 0; c < COLS; ++c) x[c] = 0.f;
      }
      #pragma unroll
      for (int c = 0; c < COLS; ++c) sc[t][c * 64 + lane] = x[c];
      #pragma unroll
      for (int off = 1; off < 64; off <<= 1) ls += __shfl_xor(ls, off);
      if (lane == 0) {
        pM[(bh * NC + chunk) * Uc + t] = ml;
        pL[(bh * NC + chunk) * Uc + t] = ls;
      }
    }
  }
  __syncthreads();
  {
    int ty = tid >> 4, tx = tid & 15;
    float4 o0 = {0.f, 0.f, 0.f, 0.f};
    float4 o1 = {0.f, 0.f, 0.f, 0.f};
    float4 o2 = {0.f, 0.f, 0.f, 0.f};
    const float4* V4 = (const float4*)V;
    int vbase = (b * Lc + chunk * CH) * (Hc * 16) + h * 16 + tx;
    #pragma unroll 4
    for (int k = 0; k < CH; ++k) {
      float4 v4 = V4[vbase + k * (Hc * 16)];
      float p0 = sc[ty][k], p1 = sc[ty + 16][k], p2 = sc[ty + 32][k];
      o0.x += p0 * v4.x; o0.y += p0 * v4.y; o0.z += p0 * v4.z; o0.w += p0 * v4.w;
      o1.x += p1 * v4.x; o1.y += p1 * v4.y; o1.z += p1 * v4.z; o1.w += p1 * v4.w;
      o2.x += p2 * v4.x; o2.y += p2 * v4.y; o2.z += p2 * v4.z; o2.w += p2 * v4.w;
    }
    float4* pO4 = (float4*)pO;
    int obase = ((bh * NC + chunk) * Uc) * 16 + tx;
    pO4[obase + ty * 16] = o0;
    pO4[obase + (ty + 16) * 16] = o1;
    if (ty < 13) pO4[obase + (ty + 32) * 16] = o2;
  }
}

// Exact merge of chunk partials; out[b][t][h][d].
template<int NC>
__global__ __launch_bounds__(256) void k_merge(const float* __restrict__ pO, const float* __restrict__ pM,
                                               const float* __restrict__ pL, float* __restrict__ out) {
  int f = blockIdx.x * 256 + threadIdx.x;   // 180*256 == 46080
  int d = f & 63, h = (f >> 6) & 7;
  int bt = f >> 9;
  int t = bt % Uc, b = bt / Uc;
  int bh = b * 8 + h;
  float m = -INFINITY;
  for (int c = 0; c < NC; ++c) m = fmaxf(m, pM[(bh * NC + c) * Uc + t]);
  float den = 0.f, num = 0.f;
  for (int c = 0; c < NC; ++c) {
    float mc = pM[(bh * NC + c) * Uc + t];
    float wgt = (mc == -INFINITY) ? 0.f : __expf(mc - m);
    den += wgt * pL[(bh * NC + c) * Uc + t];
    num += wgt * pO[((bh * NC + c) * Uc + t) * 64 + d];
  }
  out[f] = num / den;
}

extern "C" void kernel_launch(void* const* d_in, const int* in_sizes, int n_in,
                              void* d_out, int out_size, void* d_ws, size_t ws_size,
                              hipStream_t stream) {
  const float* Q = (const float*)d_in[0];
  const float* K = (const float*)d_in[1];
  const float* V = (const float*)d_in[2];
  const int* amask = (const int*)d_in[3];
  float* out = (float*)d_out;
  char* ws = (char*)d_ws;
  // ws layout:
  int*   idx  = (int*)(ws + 0x000000);     // 184320 ints (737,280 B)
  float* M    = (float*)(ws + 0x0B4000);   // 65536 floats
  int*   topk = (int*)(ws + 0x0F4000);     // 720 ints
  float* cv   = (float*)(ws + 0x0F5000);   // 5760 floats
  int*   ci   = (int*)(ws + 0x0FB000);     // 5760 ints
  float* pM   = (float*)(ws + 0x101000);   // 16*NC*45 floats
  // ws_size is constant across calls -> branch is deterministic (graph-safe).
  size_t need64 = 0x101000UL + 64UL * 190080UL;   // pM+pL+pO for NC=64 (~13.2 MB)
  size_t need32 = 0x101000UL + 32UL * 190080UL;
  int NC = ws_size >= need64 ? 64 : (ws_size >= need32 ? 32 : 16);
  float* pL = pM + 16 * NC * Uc;
  float* pO = pL + 16 * NC * Uc;

  k_idx<<<720, 256, 0, stream>>>(idx);
  k_scoreM<<<4096, 256, 0, stream>>>(Q, K, idx, M);
  k_topk1<<<dim3(8, BHc), 64, 0, stream>>>(M, cv, ci);
  k_topk2<<<BHc, 64, 0, stream>>>(cv, ci, topk);
  if (NC == 64) {
    k_attn<64><<<dim3(64, BHc), 256, 0, stream>>>(Q, K, V, amask, topk, pO, pM, pL);
    k_merge<64><<<180, 256, 0, stream>>>(pO, pM, pL, out);
  } else if (NC == 32) {
    k_attn<32><<<dim3(32, BHc), 256, 0, stream>>>(Q, K, V, amask, topk, pO, pM, pL);
    k_merge<32><<<180, 256, 0, stream>>>(pO, pM, pL, out);
  } else {
    k_attn<16><<<dim3(16, BHc), 256, 0, stream>>>(Q, K, V, amask, topk, pO, pM, pL);
    k_merge<16><<<180, 256, 0, stream>>>(pO, pM, pL, out);
  }
}

// Round 3
// 229.652 us; speedup vs baseline: 1.0653x; 1.0645x over previous
//
#include <hip/hip_runtime.h>
#include <math.h>

// ProbSparse attention (Informer). B=2 L=4096 H=8 D=64, U_part=u=45.
// R2: k_scoreM XCD-local bh mapping (bh = blockIdx&15 -> K slice L2-resident
// per XCD), shuffle-pair + LDS-transpose reduce (20 KB LDS, 7 blocks/CU),
// idx staged in LDS; k_topk two-stage fused into one kernel.
#define JAX_PARTITIONABLE 1

constexpr int Bc = 2, Lc = 4096, Hc = 8, Dc = 64;
constexpr int BHc = Bc * Hc;     // 16
constexpr int Uc = 45;           // top-k queries
constexpr int NSc = 45;          // samples per query

struct TF2 { unsigned a, b; };

__host__ __device__ constexpr unsigned rotl32(unsigned v, int n) {
  return (v << n) | (v >> (32 - n));
}

// Threefry-2x32, 20 rounds (JAX reference schedule).
__host__ __device__ constexpr TF2 tf2(unsigned k0, unsigned k1, unsigned x0, unsigned x1) {
  unsigned ks2 = k0 ^ k1 ^ 0x1BD11BDAu;
  x0 += k0; x1 += k1;
  x0 += x1; x1 = rotl32(x1, 13); x1 ^= x0;
  x0 += x1; x1 = rotl32(x1, 15); x1 ^= x0;
  x0 += x1; x1 = rotl32(x1, 26); x1 ^= x0;
  x0 += x1; x1 = rotl32(x1, 6);  x1 ^= x0;
  x0 += k1; x1 += ks2 + 1u;
  x0 += x1; x1 = rotl32(x1, 17); x1 ^= x0;
  x0 += x1; x1 = rotl32(x1, 29); x1 ^= x0;
  x0 += x1; x1 = rotl32(x1, 16); x1 ^= x0;
  x0 += x1; x1 = rotl32(x1, 24); x1 ^= x0;
  x0 += ks2; x1 += k0 + 2u;
  x0 += x1; x1 = rotl32(x1, 13); x1 ^= x0;
  x0 += x1; x1 = rotl32(x1, 15); x1 ^= x0;
  x0 += x1; x1 = rotl32(x1, 26); x1 ^= x0;
  x0 += x1; x1 = rotl32(x1, 6);  x1 ^= x0;
  x0 += k0; x1 += k1 + 3u;
  x0 += x1; x1 = rotl32(x1, 17); x1 ^= x0;
  x0 += x1; x1 = rotl32(x1, 29); x1 ^= x0;
  x0 += x1; x1 = rotl32(x1, 16); x1 ^= x0;
  x0 += x1; x1 = rotl32(x1, 24); x1 ^= x0;
  x0 += k1; x1 += ks2 + 4u;
  x0 += x1; x1 = rotl32(x1, 13); x1 ^= x0;
  x0 += x1; x1 = rotl32(x1, 15); x1 ^= x0;
  x0 += x1; x1 = rotl32(x1, 26); x1 ^= x0;
  x0 += x1; x1 = rotl32(x1, 6);  x1 ^= x0;
  x0 += ks2; x1 += k0 + 5u;
  return TF2{x0, x1};
}

__global__ __launch_bounds__(256) void k_idx(int* __restrict__ idx) {
  int f = blockIdx.x * 256 + threadIdx.x;
  constexpr TF2 kb = tf2(0u, 1u, 0u, 1u);
  TF2 r = tf2(kb.a, kb.b, 0u, (unsigned)f);
  idx[f] = (int)((r.a ^ r.b) & 4095u);
}

// M[bh][q] = max_s dot(Q[q],K[idx[q][s]]) - sum_s(...)/4096.
// bh = blockIdx&15: with round-robin block->XCD dispatch, all blocks of a bh
// share one XCD, so K[bh] (1 MB) + partner bh (1 MB) stay L2-resident (4 MiB).
// Per (q,s): 16 lanes x 4 floats -> 2 shfl_xor -> 4 subgroup sums -> LDS
// (stride-5 rows: odd stride = free 2-way alias on transpose read).
__global__ __launch_bounds__(256) void k_scoreM(const float* __restrict__ Q, const float* __restrict__ K,
                                                const int* __restrict__ idx, float* __restrict__ M) {
  __shared__ float sp[720 * 5];    // [(qloc*45+s)*5 + g], g = subgroup 0..3
  __shared__ float ps[720];        // full dot per (qloc,s)
  __shared__ int sidx[720];
  int tid = threadIdx.x;
  int bx = blockIdx.x;
  int bh = bx & 15;
  int qblk = bx >> 4;              // 0..255
  int b = bh >> 3, h = bh & 7;
  int lane16 = tid & 15, qloc = tid >> 4;
  int q = qblk * 16 + qloc;
  for (int e = tid; e < 720; e += 256) sidx[e] = idx[qblk * 720 + e];  // rows contiguous: q=qblk*16+t
  __syncthreads();
  const float4* Q4 = (const float4*)Q;
  const float4* K4 = (const float4*)K;
  float4 qr = Q4[((b * Lc + q) * Hc + h) * 16 + lane16];
  int kbase = (b * Lc * Hc + h) * 16 + lane16;
  const int* ip = sidx + qloc * NSc;
  float* wr = sp + (qloc * NSc) * 5 + (lane16 >> 2);
  bool wlane = (lane16 & 3) == 0;
  #pragma unroll 9
  for (int s = 0; s < NSc; ++s) {
    int kk = ip[s];
    float4 kv = K4[kbase + kk * (Hc * 16)];
    float p = qr.x * kv.x + qr.y * kv.y + qr.z * kv.z + qr.w * kv.w;
    p += __shfl_xor(p, 1);
    p += __shfl_xor(p, 2);
    if (wlane) wr[s * 5] = p;
  }
  __syncthreads();
  for (int p = tid; p < 720; p += 256) {
    const float* r = sp + p * 5;
    ps[p] = (r[0] + r[1]) + (r[2] + r[3]);
  }
  __syncthreads();
  if (tid < 16) {
    const float* r = ps + tid * NSc;
    float mx = r[0], sm = r[0];
    for (int s = 1; s < NSc; ++s) { float v = r[s]; mx = fmaxf(mx, v); sm += v; }
    M[bh * Lc + qblk * 16 + tid] = mx - sm * (1.0f / Lc);
  }
}

// Fused top_k (jax.lax.top_k semantics: value desc, index asc on ties).
// One block per bh, 8 waves: wave w = segment of 512, local top-45 -> LDS;
// wave 0 merges 360 candidates -> global top-45.
__global__ __launch_bounds__(512) void k_topk(const float* __restrict__ M, int* __restrict__ topk) {
  __shared__ float scv[8 * Uc];
  __shared__ int sci[8 * Uc];
  int bh = blockIdx.x;
  int tid = threadIdx.x;
  int w = tid >> 6, lane = tid & 63;
  const float* m = M + bh * Lc + w * 512;
  float v[8];
  #pragma unroll
  for (int j = 0; j < 8; ++j) v[j] = m[j * 64 + lane];
  int base = w * 512;
  for (int it = 0; it < Uc; ++it) {
    float bv = v[0]; int bj = 0;
    #pragma unroll
    for (int j = 1; j < 8; ++j) if (v[j] > bv) { bv = v[j]; bj = j; }  // strict >: lowest idx on tie
    int bi = base + bj * 64 + lane;
    #pragma unroll
    for (int off = 1; off < 64; off <<= 1) {
      float ov = __shfl_xor(bv, off);
      int oi = __shfl_xor(bi, off);
      if (ov > bv || (ov == bv && oi < bi)) { bv = ov; bi = oi; }
    }
    int r = bi - base;
    if ((r & 63) == lane) v[r >> 6] = -INFINITY;
    if (lane == 0) { scv[w * Uc + it] = bv; sci[w * Uc + it] = bi; }
  }
  __syncthreads();
  if (w == 0) {
    float cv[6]; int ci[6];
    #pragma unroll
    for (int j = 0; j < 6; ++j) {
      int p = j * 64 + lane;
      bool ok = p < 8 * Uc;
      cv[j] = ok ? scv[p] : -INFINITY;
      ci[j] = ok ? sci[p] : 0x7fffffff;
    }
    for (int it = 0; it < Uc; ++it) {
      float bv = cv[0]; int bi = ci[0];
      #pragma unroll
      for (int j = 1; j < 6; ++j)
        if (cv[j] > bv || (cv[j] == bv && ci[j] < bi)) { bv = cv[j]; bi = ci[j]; }
      #pragma unroll
      for (int off = 1; off < 64; off <<= 1) {
        float ov = __shfl_xor(bv, off);
        int oi = __shfl_xor(bi, off);
        if (ov > bv || (ov == bv && oi < bi)) { bv = ov; bi = oi; }
      }
      #pragma unroll
      for (int j = 0; j < 6; ++j) if (ci[j] == bi) cv[j] = -INFINITY;
      if (lane == 0) topk[bh * Uc + it] = bi;
    }
  }
}

// Flash-decoding partials: one block per (bh, CH-key chunk), CH = 4096/NC.
template<int NC>
__global__ __launch_bounds__(256) void k_attn(const float* __restrict__ Q, const float* __restrict__ K,
                                              const float* __restrict__ V, const int* __restrict__ amask,
                                              const int* __restrict__ topk,
                                              float* __restrict__ pO, float* __restrict__ pM,
                                              float* __restrict__ pL) {
  constexpr int CH = Lc / NC;
  constexpr int TG = 256 / CH;
  int chunk = blockIdx.x, bh = blockIdx.y;
  int b = bh >> 3, h = bh & 7;
  int tid = threadIdx.x;
  __shared__ int tk[Uc];
  __shared__ __align__(16) float qs[Uc * 64];
  __shared__ float sc[48][CH + 1];
  if (tid < Uc) tk[tid] = topk[bh * Uc + tid];
  __syncthreads();
  for (int e = tid; e < Uc * 64; e += 256) {
    int t = e >> 6, d = e & 63;
    qs[e] = Q[((b * Lc + tk[t]) * Hc + h) * Dc + d];
  }
  for (int e = tid; e < 3 * CH; e += 256) sc[45 + e / CH][e % CH] = 0.f;
  __syncthreads();
  {
    int k = tid % CH, tg = tid / CH;
    int key = chunk * CH + k;
    const float4* K4 = (const float4*)K;
    int kb = ((b * Lc + key) * Hc + h) * 16;
    float4 kr[16];
    #pragma unroll
    for (int j = 0; j < 16; ++j) kr[j] = K4[kb + j];
    int mk = amask[b * Lc + key];
    const float4* qs4 = (const float4*)qs;
    for (int t = tg; t < Uc; t += TG) {
      float acc = 0.f;
      #pragma unroll
      for (int j = 0; j < 16; ++j) {
        float4 qv = qs4[t * 16 + j];
        acc += qv.x * kr[j].x;
        acc += qv.y * kr[j].y;
        acc += qv.z * kr[j].z;
        acc += qv.w * kr[j].w;
      }
      sc[t][k] = mk ? acc * 0.125f : -INFINITY;
    }
  }
  __syncthreads();
  {
    constexpr int COLS = CH / 64;
    int w = tid >> 6, lane = tid & 63;
    for (int t = w; t < Uc; t += 4) {
      float x[COLS];
      float ml = -INFINITY;
      #pragma unroll
      for (int c = 0; c < COLS; ++c) { x[c] = sc[t][c * 64 + lane]; ml = fmaxf(ml, x[c]); }
      #pragma unroll
      for (int off = 1; off < 64; off <<= 1) ml = fmaxf(ml, __shfl_xor(ml, off));
      float ls = 0.f;
      if (ml != -INFINITY) {
        #pragma unroll
        for (int c = 0; c < COLS; ++c) { x[c] = __expf(x[c] - ml); ls += x[c]; }
      } else {
        #pragma unroll
        for (int c = 0; c < COLS; ++c) x[c] = 0.f;
      }
      #pragma unroll
      for (int c = 0; c < COLS; ++c) sc[t][c * 64 + lane] = x[c];
      #pragma unroll
      for (int off = 1; off < 64; off <<= 1) ls += __shfl_xor(ls, off);
      if (lane == 0) {
        pM[(bh * NC + chunk) * Uc + t] = ml;
        pL[(bh * NC + chunk) * Uc + t] = ls;
      }
    }
  }
  __syncthreads();
  {
    int ty = tid >> 4, tx = tid & 15;
    float4 o0 = {0.f, 0.f, 0.f, 0.f};
    float4 o1 = {0.f, 0.f, 0.f, 0.f};
    float4 o2 = {0.f, 0.f, 0.f, 0.f};
    const float4* V4 = (const float4*)V;
    int vbase = (b * Lc + chunk * CH) * (Hc * 16) + h * 16 + tx;
    #pragma unroll 4
    for (int k = 0; k < CH; ++k) {
      float4 v4 = V4[vbase + k * (Hc * 16)];
      float p0 = sc[ty][k], p1 = sc[ty + 16][k], p2 = sc[ty + 32][k];
      o0.x += p0 * v4.x; o0.y += p0 * v4.y; o0.z += p0 * v4.z; o0.w += p0 * v4.w;
      o1.x += p1 * v4.x; o1.y += p1 * v4.y; o1.z += p1 * v4.z; o1.w += p1 * v4.w;
      o2.x += p2 * v4.x; o2.y += p2 * v4.y; o2.z += p2 * v4.z; o2.w += p2 * v4.w;
    }
    float4* pO4 = (float4*)pO;
    int obase = ((bh * NC + chunk) * Uc) * 16 + tx;
    pO4[obase + ty * 16] = o0;
    pO4[obase + (ty + 16) * 16] = o1;
    if (ty < 13) pO4[obase + (ty + 32) * 16] = o2;
  }
}

// Exact merge of chunk partials; out[b][t][h][d].
template<int NC>
__global__ __launch_bounds__(256) void k_merge(const float* __restrict__ pO, const float* __restrict__ pM,
                                               const float* __restrict__ pL, float* __restrict__ out) {
  int f = blockIdx.x * 256 + threadIdx.x;   // 180*256 == 46080
  int d = f & 63, h = (f >> 6) & 7;
  int bt = f >> 9;
  int t = bt % Uc, b = bt / Uc;
  int bh = b * 8 + h;
  float m = -INFINITY;
  for (int c = 0; c < NC; ++c) m = fmaxf(m, pM[(bh * NC + c) * Uc + t]);
  float den = 0.f, num = 0.f;
  for (int c = 0; c < NC; ++c) {
    float mc = pM[(bh * NC + c) * Uc + t];
    float wgt = (mc == -INFINITY) ? 0.f : __expf(mc - m);
    den += wgt * pL[(bh * NC + c) * Uc + t];
    num += wgt * pO[((bh * NC + c) * Uc + t) * 64 + d];
  }
  out[f] = num / den;
}

extern "C" void kernel_launch(void* const* d_in, const int* in_sizes, int n_in,
                              void* d_out, int out_size, void* d_ws, size_t ws_size,
                              hipStream_t stream) {
  const float* Q = (const float*)d_in[0];
  const float* K = (const float*)d_in[1];
  const float* V = (const float*)d_in[2];
  const int* amask = (const int*)d_in[3];
  float* out = (float*)d_out;
  char* ws = (char*)d_ws;
  int*   idx  = (int*)(ws + 0x000000);     // 184320 ints (737,280 B)
  float* M    = (float*)(ws + 0x0B4000);   // 65536 floats
  int*   topk = (int*)(ws + 0x0F4000);     // 720 ints
  float* pM   = (float*)(ws + 0x101000);
  // ws_size is constant across calls -> branch is deterministic (graph-safe).
  size_t need64 = 0x101000UL + 64UL * 190080UL;   // pM+pL+pO for NC=64 (~13.2 MB)
  size_t need32 = 0x101000UL + 32UL * 190080UL;
  int NC = ws_size >= need64 ? 64 : (ws_size >= need32 ? 32 : 16);
  float* pL = pM + 16 * NC * Uc;
  float* pO = pL + 16 * NC * Uc;

  k_idx<<<720, 256, 0, stream>>>(idx);
  k_scoreM<<<4096, 256, 0, stream>>>(Q, K, idx, M);
  k_topk<<<BHc, 512, 0, stream>>>(M, topk);
  if (NC == 64) {
    k_attn<64><<<dim3(64, BHc), 256, 0, stream>>>(Q, K, V, amask, topk, pO, pM, pL);
    k_merge<64><<<180, 256, 0, stream>>>(pO, pM, pL, out);
  } else if (NC == 32) {
    k_attn<32><<<dim3(32, BHc), 256, 0, stream>>>(Q, K, V, amask, topk, pO, pM, pL);
    k_merge<32><<<180, 256, 0, stream>>>(pO, pM, pL, out);
  } else {
    k_attn<16><<<dim3(16, BHc), 256, 0, stream>>>(Q, K, V, amask, topk, pO, pM, pL);
    k_merge<16><<<180, 256, 0, stream>>>(pO, pM, pL, out);
  }
}

// Round 4
// 184.803 us; speedup vs baseline: 1.3238x; 1.2427x over previous
//
#include <hip/hip_runtime.h>
#include <math.h>

// ProbSparse attention (Informer). B=2 L=4096 H=8 D=64, U_part=u=45.
// R3: k_topk rewritten as 4-pass radix-select (was 45-iter extract-max,
// 66 us pure-latency at 0.75% occupancy). Exact lax.top_k semantics:
// value desc, index asc on ties (ties handled exactly up to 64-way).
#define JAX_PARTITIONABLE 1

constexpr int Bc = 2, Lc = 4096, Hc = 8, Dc = 64;
constexpr int BHc = Bc * Hc;     // 16
constexpr int Uc = 45;           // top-k queries
constexpr int NSc = 45;          // samples per query

struct TF2 { unsigned a, b; };

__host__ __device__ constexpr unsigned rotl32(unsigned v, int n) {
  return (v << n) | (v >> (32 - n));
}

// Threefry-2x32, 20 rounds (JAX reference schedule).
__host__ __device__ constexpr TF2 tf2(unsigned k0, unsigned k1, unsigned x0, unsigned x1) {
  unsigned ks2 = k0 ^ k1 ^ 0x1BD11BDAu;
  x0 += k0; x1 += k1;
  x0 += x1; x1 = rotl32(x1, 13); x1 ^= x0;
  x0 += x1; x1 = rotl32(x1, 15); x1 ^= x0;
  x0 += x1; x1 = rotl32(x1, 26); x1 ^= x0;
  x0 += x1; x1 = rotl32(x1, 6);  x1 ^= x0;
  x0 += k1; x1 += ks2 + 1u;
  x0 += x1; x1 = rotl32(x1, 17); x1 ^= x0;
  x0 += x1; x1 = rotl32(x1, 29); x1 ^= x0;
  x0 += x1; x1 = rotl32(x1, 16); x1 ^= x0;
  x0 += x1; x1 = rotl32(x1, 24); x1 ^= x0;
  x0 += ks2; x1 += k0 + 2u;
  x0 += x1; x1 = rotl32(x1, 13); x1 ^= x0;
  x0 += x1; x1 = rotl32(x1, 15); x1 ^= x0;
  x0 += x1; x1 = rotl32(x1, 26); x1 ^= x0;
  x0 += x1; x1 = rotl32(x1, 6);  x1 ^= x0;
  x0 += k0; x1 += k1 + 3u;
  x0 += x1; x1 = rotl32(x1, 17); x1 ^= x0;
  x0 += x1; x1 = rotl32(x1, 29); x1 ^= x0;
  x0 += x1; x1 = rotl32(x1, 16); x1 ^= x0;
  x0 += x1; x1 = rotl32(x1, 24); x1 ^= x0;
  x0 += k1; x1 += ks2 + 4u;
  x0 += x1; x1 = rotl32(x1, 13); x1 ^= x0;
  x0 += x1; x1 = rotl32(x1, 15); x1 ^= x0;
  x0 += x1; x1 = rotl32(x1, 26); x1 ^= x0;
  x0 += x1; x1 = rotl32(x1, 6);  x1 ^= x0;
  x0 += ks2; x1 += k0 + 5u;
  return TF2{x0, x1};
}

__global__ __launch_bounds__(256) void k_idx(int* __restrict__ idx) {
  int f = blockIdx.x * 256 + threadIdx.x;
  constexpr TF2 kb = tf2(0u, 1u, 0u, 1u);
  TF2 r = tf2(kb.a, kb.b, 0u, (unsigned)f);
  idx[f] = (int)((r.a ^ r.b) & 4095u);
}

// M[bh][q] = max_s dot(Q[q],K[idx[q][s]]) - sum_s(...)/4096.
// bh = blockIdx&15: with round-robin block->XCD dispatch, all blocks of a bh
// share one XCD, so the K slice stays L2-resident.
__global__ __launch_bounds__(256) void k_scoreM(const float* __restrict__ Q, const float* __restrict__ K,
                                                const int* __restrict__ idx, float* __restrict__ M) {
  __shared__ float sp[720 * 5];    // [(qloc*45+s)*5 + g], g = subgroup 0..3
  __shared__ float ps[720];        // full dot per (qloc,s)
  __shared__ int sidx[720];
  int tid = threadIdx.x;
  int bx = blockIdx.x;
  int bh = bx & 15;
  int qblk = bx >> 4;              // 0..255
  int b = bh >> 3, h = bh & 7;
  int lane16 = tid & 15, qloc = tid >> 4;
  int q = qblk * 16 + qloc;
  for (int e = tid; e < 720; e += 256) sidx[e] = idx[qblk * 720 + e];
  __syncthreads();
  const float4* Q4 = (const float4*)Q;
  const float4* K4 = (const float4*)K;
  float4 qr = Q4[((b * Lc + q) * Hc + h) * 16 + lane16];
  int kbase = (b * Lc * Hc + h) * 16 + lane16;
  const int* ip = sidx + qloc * NSc;
  float* wr = sp + (qloc * NSc) * 5 + (lane16 >> 2);
  bool wlane = (lane16 & 3) == 0;
  #pragma unroll 9
  for (int s = 0; s < NSc; ++s) {
    int kk = ip[s];
    float4 kv = K4[kbase + kk * (Hc * 16)];
    float p = qr.x * kv.x + qr.y * kv.y + qr.z * kv.z + qr.w * kv.w;
    p += __shfl_xor(p, 1);
    p += __shfl_xor(p, 2);
    if (wlane) wr[s * 5] = p;
  }
  __syncthreads();
  for (int p = tid; p < 720; p += 256) {
    const float* r = sp + p * 5;
    ps[p] = (r[0] + r[1]) + (r[2] + r[3]);
  }
  __syncthreads();
  if (tid < 16) {
    const float* r = ps + tid * NSc;
    float mx = r[0], sm = r[0];
    for (int s = 1; s < NSc; ++s) { float v = r[s]; mx = fmaxf(mx, v); sm += v; }
    M[bh * Lc + qblk * 16 + tid] = mx - sm * (1.0f / Lc);
  }
}

// Radix-select top-45 of 4096 per bh. Monotone map: desc float order ==
// desc uint order. 4 passes of 8-bit digits (MSB first): LDS histogram ->
// suffix-scan -> digit pick. Then gather >T plus rf smallest-index ==T,
// rank-sort 45 candidates (value desc, index asc) = exact lax.top_k.
__global__ __launch_bounds__(256) void k_topk(const float* __restrict__ M, int* __restrict__ topk) {
  __shared__ unsigned su[Lc];      // 16 KB mapped keys
  __shared__ int hist[256];
  __shared__ int sfx[257];
  __shared__ unsigned s_prefix;
  __shared__ int s_r;
  __shared__ int n_gt, n_eq;
  __shared__ unsigned cu[64];
  __shared__ int cidx[64];
  __shared__ int eqi[64];
  int bh = blockIdx.x, tid = threadIdx.x;
  const float* m = M + bh * Lc;
  for (int e = tid; e < Lc; e += 256) {
    unsigned bb = __float_as_uint(m[e]);
    su[e] = (bb & 0x80000000u) ? ~bb : (bb | 0x80000000u);
  }
  if (tid == 0) { s_r = Uc; s_prefix = 0u; n_gt = 0; n_eq = 0; }
  __syncthreads();
  #pragma unroll
  for (int p = 0; p < 4; ++p) {
    int shift = 24 - 8 * p;
    hist[tid] = 0;
    __syncthreads();
    unsigned pref = s_prefix;
    unsigned hmask = (p == 0) ? 0u : (0xFFFFFFFFu << (shift + 8));
    for (int e = tid; e < Lc; e += 256) {
      unsigned u = su[e];
      if ((u & hmask) == pref) atomicAdd(&hist[(u >> shift) & 255u], 1);
    }
    __syncthreads();
    sfx[tid] = hist[tid];
    __syncthreads();
    for (int off = 1; off < 256; off <<= 1) {   // inclusive suffix sum
      int v = (tid + off < 256) ? sfx[tid + off] : 0;
      __syncthreads();
      sfx[tid] += v;
      __syncthreads();
    }
    int r = s_r;
    __syncthreads();                            // all read s_r before update
    int above = (tid < 255) ? sfx[tid + 1] : 0;
    if (sfx[tid] >= r && above < r) {           // unique digit
      s_r = r - above;
      s_prefix = pref | ((unsigned)tid << shift);
    }
    __syncthreads();
  }
  unsigned T = s_prefix;                        // exact 45th-largest key
  int rf = s_r;                                 // #equals to take (>=1)
  for (int e = tid; e < Lc; e += 256) {
    unsigned u = su[e];
    if (u > T) {
      int p = atomicAdd(&n_gt, 1);              // <= 44
      cu[p] = u; cidx[p] = e;
    } else if (u == T) {
      int p = atomicAdd(&n_eq, 1);
      if (p < 64) eqi[p] = e;                   // ties beyond 64-way: impossible for random-normal M
    }
  }
  __syncthreads();
  int ne = n_eq < 64 ? n_eq : 64;
  if (tid < ne) {
    int myi = eqi[tid];
    int rank = 0;
    for (int j = 0; j < ne; ++j) rank += (eqi[j] < myi);
    if (rank < rf) {
      int p = atomicAdd(&n_gt, 1);              // completes to exactly 45
      cu[p] = T; cidx[p] = myi;
    }
  }
  __syncthreads();
  if (tid < Uc) {
    unsigned mu = cu[tid]; int mi = cidx[tid];
    int rank = 0;
    for (int j = 0; j < Uc; ++j) {
      unsigned ju = cu[j]; int ji = cidx[j];
      rank += (ju > mu) || (ju == mu && ji < mi);
    }
    topk[bh * Uc + rank] = mi;
  }
}

// Flash-decoding partials: one block per (bh, CH-key chunk), CH = 4096/NC.
template<int NC>
__global__ __launch_bounds__(256) void k_attn(const float* __restrict__ Q, const float* __restrict__ K,
                                              const float* __restrict__ V, const int* __restrict__ amask,
                                              const int* __restrict__ topk,
                                              float* __restrict__ pO, float* __restrict__ pM,
                                              float* __restrict__ pL) {
  constexpr int CH = Lc / NC;
  constexpr int TG = 256 / CH;
  int chunk = blockIdx.x, bh = blockIdx.y;
  int b = bh >> 3, h = bh & 7;
  int tid = threadIdx.x;
  __shared__ int tk[Uc];
  __shared__ __align__(16) float qs[Uc * 64];
  __shared__ float sc[48][CH + 1];
  if (tid < Uc) tk[tid] = topk[bh * Uc + tid];
  __syncthreads();
  for (int e = tid; e < Uc * 64; e += 256) {
    int t = e >> 6, d = e & 63;
    qs[e] = Q[((b * Lc + tk[t]) * Hc + h) * Dc + d];
  }
  for (int e = tid; e < 3 * CH; e += 256) sc[45 + e / CH][e % CH] = 0.f;
  __syncthreads();
  {
    int k = tid % CH, tg = tid / CH;
    int key = chunk * CH + k;
    const float4* K4 = (const float4*)K;
    int kb = ((b * Lc + key) * Hc + h) * 16;
    float4 kr[16];
    #pragma unroll
    for (int j = 0; j < 16; ++j) kr[j] = K4[kb + j];
    int mk = amask[b * Lc + key];
    const float4* qs4 = (const float4*)qs;
    for (int t = tg; t < Uc; t += TG) {
      float acc = 0.f;
      #pragma unroll
      for (int j = 0; j < 16; ++j) {
        float4 qv = qs4[t * 16 + j];
        acc += qv.x * kr[j].x;
        acc += qv.y * kr[j].y;
        acc += qv.z * kr[j].z;
        acc += qv.w * kr[j].w;
      }
      sc[t][k] = mk ? acc * 0.125f : -INFINITY;
    }
  }
  __syncthreads();
  {
    constexpr int COLS = CH / 64;
    int w = tid >> 6, lane = tid & 63;
    for (int t = w; t < Uc; t += 4) {
      float x[COLS];
      float ml = -INFINITY;
      #pragma unroll
      for (int c = 0; c < COLS; ++c) { x[c] = sc[t][c * 64 + lane]; ml = fmaxf(ml, x[c]); }
      #pragma unroll
      for (int off = 1; off < 64; off <<= 1) ml = fmaxf(ml, __shfl_xor(ml, off));
      float ls = 0.f;
      if (ml != -INFINITY) {
        #pragma unroll
        for (int c = 0; c < COLS; ++c) { x[c] = __expf(x[c] - ml); ls += x[c]; }
      } else {
        #pragma unroll
        for (int c = 0; c < COLS; ++c) x[c] = 0.f;
      }
      #pragma unroll
      for (int c = 0; c < COLS; ++c) sc[t][c * 64 + lane] = x[c];
      #pragma unroll
      for (int off = 1; off < 64; off <<= 1) ls += __shfl_xor(ls, off);
      if (lane == 0) {
        pM[(bh * NC + chunk) * Uc + t] = ml;
        pL[(bh * NC + chunk) * Uc + t] = ls;
      }
    }
  }
  __syncthreads();
  {
    int ty = tid >> 4, tx = tid & 15;
    float4 o0 = {0.f, 0.f, 0.f, 0.f};
    float4 o1 = {0.f, 0.f, 0.f, 0.f};
    float4 o2 = {0.f, 0.f, 0.f, 0.f};
    const float4* V4 = (const float4*)V;
    int vbase = (b * Lc + chunk * CH) * (Hc * 16) + h * 16 + tx;
    #pragma unroll 4
    for (int k = 0; k < CH; ++k) {
      float4 v4 = V4[vbase + k * (Hc * 16)];
      float p0 = sc[ty][k], p1 = sc[ty + 16][k], p2 = sc[ty + 32][k];
      o0.x += p0 * v4.x; o0.y += p0 * v4.y; o0.z += p0 * v4.z; o0.w += p0 * v4.w;
      o1.x += p1 * v4.x; o1.y += p1 * v4.y; o1.z += p1 * v4.z; o1.w += p1 * v4.w;
      o2.x += p2 * v4.x; o2.y += p2 * v4.y; o2.z += p2 * v4.z; o2.w += p2 * v4.w;
    }
    float4* pO4 = (float4*)pO;
    int obase = ((bh * NC + chunk) * Uc) * 16 + tx;
    pO4[obase + ty * 16] = o0;
    pO4[obase + (ty + 16) * 16] = o1;
    if (ty < 13) pO4[obase + (ty + 32) * 16] = o2;
  }
}

// Exact merge of chunk partials; out[b][t][h][d].
template<int NC>
__global__ __launch_bounds__(256) void k_merge(const float* __restrict__ pO, const float* __restrict__ pM,
                                               const float* __restrict__ pL, float* __restrict__ out) {
  int f = blockIdx.x * 256 + threadIdx.x;   // 180*256 == 46080
  int d = f & 63, h = (f >> 6) & 7;
  int bt = f >> 9;
  int t = bt % Uc, b = bt / Uc;
  int bh = b * 8 + h;
  float m = -INFINITY;
  for (int c = 0; c < NC; ++c) m = fmaxf(m, pM[(bh * NC + c) * Uc + t]);
  float den = 0.f, num = 0.f;
  for (int c = 0; c < NC; ++c) {
    float mc = pM[(bh * NC + c) * Uc + t];
    float wgt = (mc == -INFINITY) ? 0.f : __expf(mc - m);
    den += wgt * pL[(bh * NC + c) * Uc + t];
    num += wgt * pO[((bh * NC + c) * Uc + t) * 64 + d];
  }
  out[f] = num / den;
}

extern "C" void kernel_launch(void* const* d_in, const int* in_sizes, int n_in,
                              void* d_out, int out_size, void* d_ws, size_t ws_size,
                              hipStream_t stream) {
  const float* Q = (const float*)d_in[0];
  const float* K = (const float*)d_in[1];
  const float* V = (const float*)d_in[2];
  const int* amask = (const int*)d_in[3];
  float* out = (float*)d_out;
  char* ws = (char*)d_ws;
  int*   idx  = (int*)(ws + 0x000000);     // 184320 ints (737,280 B)
  float* M    = (float*)(ws + 0x0B4000);   // 65536 floats
  int*   topk = (int*)(ws + 0x0F4000);     // 720 ints
  float* pM   = (float*)(ws + 0x101000);
  // ws_size is constant across calls -> branch is deterministic (graph-safe).
  size_t need64 = 0x101000UL + 64UL * 190080UL;   // pM+pL+pO for NC=64 (~13.2 MB)
  size_t need32 = 0x101000UL + 32UL * 190080UL;
  int NC = ws_size >= need64 ? 64 : (ws_size >= need32 ? 32 : 16);
  float* pL = pM + 16 * NC * Uc;
  float* pO = pL + 16 * NC * Uc;

  k_idx<<<720, 256, 0, stream>>>(idx);
  k_scoreM<<<4096, 256, 0, stream>>>(Q, K, idx, M);
  k_topk<<<BHc, 256, 0, stream>>>(M, topk);
  if (NC == 64) {
    k_attn<64><<<dim3(64, BHc), 256, 0, stream>>>(Q, K, V, amask, topk, pO, pM, pL);
    k_merge<64><<<180, 256, 0, stream>>>(pO, pM, pL, out);
  } else if (NC == 32) {
    k_attn<32><<<dim3(32, BHc), 256, 0, stream>>>(Q, K, V, amask, topk, pO, pM, pL);
    k_merge<32><<<180, 256, 0, stream>>>(pO, pM, pL, out);
  } else {
    k_attn<16><<<dim3(16, BHc), 256, 0, stream>>>(Q, K, V, amask, topk, pO, pM, pL);
    k_merge<16><<<180, 256, 0, stream>>>(pO, pM, pL, out);
  }
}

// Round 5
// 183.501 us; speedup vs baseline: 1.3332x; 1.0071x over previous
//
#include <hip/hip_runtime.h>
#include <math.h>

// ProbSparse attention (Informer). B=2 L=4096 H=8 D=64, U_part=u=45.
// R4: k_idx fused into k_scoreM (inline threefry); scoreM inner loop batched
// 5-deep for load ILP (was 1 kv in flight -> L2-latency-bound); k_topk
// pre-gathers selected Q rows into qg so k_attn reads coalesced.
#define JAX_PARTITIONABLE 1

constexpr int Bc = 2, Lc = 4096, Hc = 8, Dc = 64;
constexpr int BHc = Bc * Hc;     // 16
constexpr int Uc = 45;           // top-k queries
constexpr int NSc = 45;          // samples per query

struct TF2 { unsigned a, b; };

__host__ __device__ constexpr unsigned rotl32(unsigned v, int n) {
  return (v << n) | (v >> (32 - n));
}

// Threefry-2x32, 20 rounds (JAX reference schedule).
__host__ __device__ constexpr TF2 tf2(unsigned k0, unsigned k1, unsigned x0, unsigned x1) {
  unsigned ks2 = k0 ^ k1 ^ 0x1BD11BDAu;
  x0 += k0; x1 += k1;
  x0 += x1; x1 = rotl32(x1, 13); x1 ^= x0;
  x0 += x1; x1 = rotl32(x1, 15); x1 ^= x0;
  x0 += x1; x1 = rotl32(x1, 26); x1 ^= x0;
  x0 += x1; x1 = rotl32(x1, 6);  x1 ^= x0;
  x0 += k1; x1 += ks2 + 1u;
  x0 += x1; x1 = rotl32(x1, 17); x1 ^= x0;
  x0 += x1; x1 = rotl32(x1, 29); x1 ^= x0;
  x0 += x1; x1 = rotl32(x1, 16); x1 ^= x0;
  x0 += x1; x1 = rotl32(x1, 24); x1 ^= x0;
  x0 += ks2; x1 += k0 + 2u;
  x0 += x1; x1 = rotl32(x1, 13); x1 ^= x0;
  x0 += x1; x1 = rotl32(x1, 15); x1 ^= x0;
  x0 += x1; x1 = rotl32(x1, 26); x1 ^= x0;
  x0 += x1; x1 = rotl32(x1, 6);  x1 ^= x0;
  x0 += k0; x1 += k1 + 3u;
  x0 += x1; x1 = rotl32(x1, 17); x1 ^= x0;
  x0 += x1; x1 = rotl32(x1, 29); x1 ^= x0;
  x0 += x1; x1 = rotl32(x1, 16); x1 ^= x0;
  x0 += x1; x1 = rotl32(x1, 24); x1 ^= x0;
  x0 += k1; x1 += ks2 + 4u;
  x0 += x1; x1 = rotl32(x1, 13); x1 ^= x0;
  x0 += x1; x1 = rotl32(x1, 15); x1 ^= x0;
  x0 += x1; x1 = rotl32(x1, 26); x1 ^= x0;
  x0 += x1; x1 = rotl32(x1, 6);  x1 ^= x0;
  x0 += ks2; x1 += k0 + 5u;
  return TF2{x0, x1};
}

// M[bh][q] = max_s dot(Q[q],K[idx[q][s]]) - sum_s(...)/4096.
// bh = blockIdx&15: with round-robin block->XCD dispatch, each XCD sees 2 bh
// -> 2 MB K slices stay L2-resident. idx computed inline (threefry).
__global__ __launch_bounds__(256) void k_scoreM(const float* __restrict__ Q, const float* __restrict__ K,
                                                float* __restrict__ M) {
  __shared__ float sp[720 * 5];    // [(qloc*45+s)*5 + g], g = subgroup 0..3
  __shared__ float ps[720];        // full dot per (qloc,s)
  __shared__ int sidx[720];
  int tid = threadIdx.x;
  int bx = blockIdx.x;
  int bh = bx & 15;
  int qblk = bx >> 4;              // 0..255
  int b = bh >> 3, h = bh & 7;
  int lane16 = tid & 15, qloc = tid >> 4;
  int q = qblk * 16 + qloc;
  constexpr TF2 kb = tf2(0u, 1u, 0u, 1u);
  for (int e = tid; e < 720; e += 256) {
    TF2 r = tf2(kb.a, kb.b, 0u, (unsigned)(qblk * 720 + e));
    sidx[e] = (int)((r.a ^ r.b) & 4095u);
  }
  __syncthreads();
  const float4* Q4 = (const float4*)Q;
  const float4* K4 = (const float4*)K;
  float4 qr = Q4[((b * Lc + q) * Hc + h) * 16 + lane16];
  int kbase = (b * Lc * Hc + h) * 16 + lane16;
  const int* ip = sidx + qloc * NSc;
  float* wr = sp + (qloc * NSc) * 5 + (lane16 >> 2);
  bool wlane = (lane16 & 3) == 0;
  #pragma unroll
  for (int s0 = 0; s0 < NSc; s0 += 5) {      // 5-deep load batch: >=5 L2 loads in flight
    int kk[5];
    #pragma unroll
    for (int i = 0; i < 5; ++i) kk[i] = ip[s0 + i];
    float4 kv[5];
    #pragma unroll
    for (int i = 0; i < 5; ++i) kv[i] = K4[kbase + kk[i] * (Hc * 16)];
    #pragma unroll
    for (int i = 0; i < 5; ++i) {
      float p = qr.x * kv[i].x + qr.y * kv[i].y + qr.z * kv[i].z + qr.w * kv[i].w;
      p += __shfl_xor(p, 1);
      p += __shfl_xor(p, 2);
      if (wlane) wr[(s0 + i) * 5] = p;
    }
  }
  __syncthreads();
  for (int p = tid; p < 720; p += 256) {
    const float* r = sp + p * 5;
    ps[p] = (r[0] + r[1]) + (r[2] + r[3]);
  }
  __syncthreads();
  if (tid < 16) {
    const float* r = ps + tid * NSc;
    float mx = r[0], sm = r[0];
    for (int s = 1; s < NSc; ++s) { float v = r[s]; mx = fmaxf(mx, v); sm += v; }
    M[bh * Lc + qblk * 16 + tid] = mx - sm * (1.0f / Lc);
  }
}

// Radix-select top-45 of 4096 per bh (exact lax.top_k: value desc, index asc
// on ties). Then pre-gather the 45 selected Q rows into qg[bh][45][64].
__global__ __launch_bounds__(256) void k_topk(const float* __restrict__ M, const float* __restrict__ Q,
                                              int* __restrict__ topk, float* __restrict__ qg) {
  __shared__ unsigned su[Lc];      // 16 KB mapped keys
  __shared__ int hist[256];
  __shared__ int sfx[257];
  __shared__ unsigned s_prefix;
  __shared__ int s_r;
  __shared__ int n_gt, n_eq;
  __shared__ unsigned cu[64];
  __shared__ int cidx[64];
  __shared__ int eqi[64];
  __shared__ int srank[Uc];
  int bh = blockIdx.x, tid = threadIdx.x;
  int b = bh >> 3, h = bh & 7;
  const float* m = M + bh * Lc;
  for (int e = tid; e < Lc; e += 256) {
    unsigned bb = __float_as_uint(m[e]);
    su[e] = (bb & 0x80000000u) ? ~bb : (bb | 0x80000000u);
  }
  if (tid == 0) { s_r = Uc; s_prefix = 0u; n_gt = 0; n_eq = 0; }
  __syncthreads();
  #pragma unroll
  for (int p = 0; p < 4; ++p) {
    int shift = 24 - 8 * p;
    hist[tid] = 0;
    __syncthreads();
    unsigned pref = s_prefix;
    unsigned hmask = (p == 0) ? 0u : (0xFFFFFFFFu << (shift + 8));
    for (int e = tid; e < Lc; e += 256) {
      unsigned u = su[e];
      if ((u & hmask) == pref) atomicAdd(&hist[(u >> shift) & 255u], 1);
    }
    __syncthreads();
    sfx[tid] = hist[tid];
    __syncthreads();
    for (int off = 1; off < 256; off <<= 1) {   // inclusive suffix sum
      int v = (tid + off < 256) ? sfx[tid + off] : 0;
      __syncthreads();
      sfx[tid] += v;
      __syncthreads();
    }
    int r = s_r;
    __syncthreads();                            // all read s_r before update
    int above = (tid < 255) ? sfx[tid + 1] : 0;
    if (sfx[tid] >= r && above < r) {           // unique digit
      s_r = r - above;
      s_prefix = pref | ((unsigned)tid << shift);
    }
    __syncthreads();
  }
  unsigned T = s_prefix;                        // exact 45th-largest key
  int rf = s_r;                                 // #equals to take (>=1)
  for (int e = tid; e < Lc; e += 256) {
    unsigned u = su[e];
    if (u > T) {
      int p = atomicAdd(&n_gt, 1);              // <= 44
      cu[p] = u; cidx[p] = e;
    } else if (u == T) {
      int p = atomicAdd(&n_eq, 1);
      if (p < 64) eqi[p] = e;                   // >64-way ties: impossible for random-normal M
    }
  }
  __syncthreads();
  int ne = n_eq < 64 ? n_eq : 64;
  if (tid < ne) {
    int myi = eqi[tid];
    int rank = 0;
    for (int j = 0; j < ne; ++j) rank += (eqi[j] < myi);
    if (rank < rf) {
      int p = atomicAdd(&n_gt, 1);              // completes to exactly 45
      cu[p] = T; cidx[p] = myi;
    }
  }
  __syncthreads();
  if (tid < Uc) {
    unsigned mu = cu[tid]; int mi = cidx[tid];
    int rank = 0;
    for (int j = 0; j < Uc; ++j) {
      unsigned ju = cu[j]; int ji = cidx[j];
      rank += (ju > mu) || (ju == mu && ji < mi);
    }
    topk[bh * Uc + rank] = mi;
    srank[rank] = mi;
  }
  __syncthreads();
  const float4* Q4 = (const float4*)Q;
  float4* qg4 = (float4*)qg;
  for (int e = tid; e < Uc * 16; e += 256) {    // coalesced pre-gather of selected Q rows
    int t = e >> 4, dq = e & 15;
    qg4[bh * Uc * 16 + e] = Q4[((b * Lc + srank[t]) * Hc + h) * 16 + dq];
  }
}

// Flash-decoding partials: one block per (bh, CH-key chunk), CH = 4096/NC.
template<int NC>
__global__ __launch_bounds__(256) void k_attn(const float* __restrict__ qg, const float* __restrict__ K,
                                              const float* __restrict__ V, const int* __restrict__ amask,
                                              float* __restrict__ pO, float* __restrict__ pM,
                                              float* __restrict__ pL) {
  constexpr int CH = Lc / NC;
  constexpr int TG = 256 / CH;
  int chunk = blockIdx.x, bh = blockIdx.y;
  int b = bh >> 3, h = bh & 7;
  int tid = threadIdx.x;
  __shared__ __align__(16) float qs[Uc * 64];
  __shared__ float sc[48][CH + 1];
  {
    const float4* qg4 = (const float4*)qg;
    float4* qs4w = (float4*)qs;
    for (int e = tid; e < Uc * 16; e += 256) qs4w[e] = qg4[bh * Uc * 16 + e];
  }
  for (int e = tid; e < 3 * CH; e += 256) sc[45 + e / CH][e % CH] = 0.f;
  __syncthreads();
  {
    int k = tid % CH, tg = tid / CH;
    int key = chunk * CH + k;
    const float4* K4 = (const float4*)K;
    int kb = ((b * Lc + key) * Hc + h) * 16;
    float4 kr[16];
    #pragma unroll
    for (int j = 0; j < 16; ++j) kr[j] = K4[kb + j];
    int mk = amask[b * Lc + key];
    const float4* qs4 = (const float4*)qs;
    for (int t = tg; t < Uc; t += TG) {
      float acc = 0.f;
      #pragma unroll
      for (int j = 0; j < 16; ++j) {
        float4 qv = qs4[t * 16 + j];
        acc += qv.x * kr[j].x;
        acc += qv.y * kr[j].y;
        acc += qv.z * kr[j].z;
        acc += qv.w * kr[j].w;
      }
      sc[t][k] = mk ? acc * 0.125f : -INFINITY;
    }
  }
  __syncthreads();
  {
    constexpr int COLS = CH / 64;
    int w = tid >> 6, lane = tid & 63;
    for (int t = w; t < Uc; t += 4) {
      float x[COLS];
      float ml = -INFINITY;
      #pragma unroll
      for (int c = 0; c < COLS; ++c) { x[c] = sc[t][c * 64 + lane]; ml = fmaxf(ml, x[c]); }
      #pragma unroll
      for (int off = 1; off < 64; off <<= 1) ml = fmaxf(ml, __shfl_xor(ml, off));
      float ls = 0.f;
      if (ml != -INFINITY) {
        #pragma unroll
        for (int c = 0; c < COLS; ++c) { x[c] = __expf(x[c] - ml); ls += x[c]; }
      } else {
        #pragma unroll
        for (int c = 0; c < COLS; ++c) x[c] = 0.f;
      }
      #pragma unroll
      for (int c = 0; c < COLS; ++c) sc[t][c * 64 + lane] = x[c];
      #pragma unroll
      for (int off = 1; off < 64; off <<= 1) ls += __shfl_xor(ls, off);
      if (lane == 0) {
        pM[(bh * NC + chunk) * Uc + t] = ml;
        pL[(bh * NC + chunk) * Uc + t] = ls;
      }
    }
  }
  __syncthreads();
  {
    int ty = tid >> 4, tx = tid & 15;
    float4 o0 = {0.f, 0.f, 0.f, 0.f};
    float4 o1 = {0.f, 0.f, 0.f, 0.f};
    float4 o2 = {0.f, 0.f, 0.f, 0.f};
    const float4* V4 = (const float4*)V;
    int vbase = (b * Lc + chunk * CH) * (Hc * 16) + h * 16 + tx;
    #pragma unroll 4
    for (int k = 0; k < CH; ++k) {
      float4 v4 = V4[vbase + k * (Hc * 16)];
      float p0 = sc[ty][k], p1 = sc[ty + 16][k], p2 = sc[ty + 32][k];
      o0.x += p0 * v4.x; o0.y += p0 * v4.y; o0.z += p0 * v4.z; o0.w += p0 * v4.w;
      o1.x += p1 * v4.x; o1.y += p1 * v4.y; o1.z += p1 * v4.z; o1.w += p1 * v4.w;
      o2.x += p2 * v4.x; o2.y += p2 * v4.y; o2.z += p2 * v4.z; o2.w += p2 * v4.w;
    }
    float4* pO4 = (float4*)pO;
    int obase = ((bh * NC + chunk) * Uc) * 16 + tx;
    pO4[obase + ty * 16] = o0;
    pO4[obase + (ty + 16) * 16] = o1;
    if (ty < 13) pO4[obase + (ty + 32) * 16] = o2;
  }
}

// Exact merge of chunk partials; out[b][t][h][d].
template<int NC>
__global__ __launch_bounds__(256) void k_merge(const float* __restrict__ pO, const float* __restrict__ pM,
                                               const float* __restrict__ pL, float* __restrict__ out) {
  int f = blockIdx.x * 256 + threadIdx.x;   // 180*256 == 46080
  int d = f & 63, h = (f >> 6) & 7;
  int bt = f >> 9;
  int t = bt % Uc, b = bt / Uc;
  int bh = b * 8 + h;
  float m = -INFINITY;
  for (int c = 0; c < NC; ++c) m = fmaxf(m, pM[(bh * NC + c) * Uc + t]);
  float den = 0.f, num = 0.f;
  for (int c = 0; c < NC; ++c) {
    float mc = pM[(bh * NC + c) * Uc + t];
    float wgt = (mc == -INFINITY) ? 0.f : __expf(mc - m);
    den += wgt * pL[(bh * NC + c) * Uc + t];
    num += wgt * pO[((bh * NC + c) * Uc + t) * 64 + d];
  }
  out[f] = num / den;
}

extern "C" void kernel_launch(void* const* d_in, const int* in_sizes, int n_in,
                              void* d_out, int out_size, void* d_ws, size_t ws_size,
                              hipStream_t stream) {
  const float* Q = (const float*)d_in[0];
  const float* K = (const float*)d_in[1];
  const float* V = (const float*)d_in[2];
  const int* amask = (const int*)d_in[3];
  float* out = (float*)d_out;
  char* ws = (char*)d_ws;
  float* M    = (float*)(ws + 0x000000);   // 65536 floats (256 KB)
  int*   topk = (int*)(ws + 0x040000);     // 720 ints
  float* qg   = (float*)(ws + 0x041000);   // 16*45*64 floats (184,320 B)
  float* pM   = (float*)(ws + 0x070000);
  // ws_size is constant across calls -> branch is deterministic (graph-safe).
  size_t need64 = 0x70000UL + 64UL * 190080UL;   // pM+pL+pO for NC=64 (~12.6 MB)
  size_t need32 = 0x70000UL + 32UL * 190080UL;
  int NC = ws_size >= need64 ? 64 : (ws_size >= need32 ? 32 : 16);
  float* pL = pM + 16 * NC * Uc;
  float* pO = pL + 16 * NC * Uc;

  k_scoreM<<<4096, 256, 0, stream>>>(Q, K, M);
  k_topk<<<BHc, 256, 0, stream>>>(M, Q, topk, qg);
  if (NC == 64) {
    k_attn<64><<<dim3(64, BHc), 256, 0, stream>>>(qg, K, V, amask, pO, pM, pL);
    k_merge<64><<<180, 256, 0, stream>>>(pO, pM, pL, out);
  } else if (NC == 32) {
    k_attn<32><<<dim3(32, BHc), 256, 0, stream>>>(qg, K, V, amask, pO, pM, pL);
    k_merge<32><<<180, 256, 0, stream>>>(pO, pM, pL, out);
  } else {
    k_attn<16><<<dim3(16, BHc), 256, 0, stream>>>(qg, K, V, amask, pO, pM, pL);
    k_merge<16><<<180, 256, 0, stream>>>(pO, pM, pL, out);
  }
}

// Round 6
// 182.521 us; speedup vs baseline: 1.3403x; 1.0054x over previous
//
#include <hip/hip_runtime.h>
#include <math.h>

// ProbSparse attention (Informer). B=2 L=4096 H=8 D=64, U_part=u=45.
// R5: k_scoreM quad-reduction moved from LDS pipe (ds_bpermute shuffles) to
// VALU pipe (v_add_f32_dpp quad_perm xor1/xor2, bit-identical association);
// K-gather loads nontemporal (single-use rows, skip L1 allocate).
#define JAX_PARTITIONABLE 1

constexpr int Bc = 2, Lc = 4096, Hc = 8, Dc = 64;
constexpr int BHc = Bc * Hc;     // 16
constexpr int Uc = 45;           // top-k queries
constexpr int NSc = 45;          // samples per query

typedef float vfloat4 __attribute__((ext_vector_type(4)));

struct TF2 { unsigned a, b; };

__host__ __device__ constexpr unsigned rotl32(unsigned v, int n) {
  return (v << n) | (v >> (32 - n));
}

// Threefry-2x32, 20 rounds (JAX reference schedule).
__host__ __device__ constexpr TF2 tf2(unsigned k0, unsigned k1, unsigned x0, unsigned x1) {
  unsigned ks2 = k0 ^ k1 ^ 0x1BD11BDAu;
  x0 += k0; x1 += k1;
  x0 += x1; x1 = rotl32(x1, 13); x1 ^= x0;
  x0 += x1; x1 = rotl32(x1, 15); x1 ^= x0;
  x0 += x1; x1 = rotl32(x1, 26); x1 ^= x0;
  x0 += x1; x1 = rotl32(x1, 6);  x1 ^= x0;
  x0 += k1; x1 += ks2 + 1u;
  x0 += x1; x1 = rotl32(x1, 17); x1 ^= x0;
  x0 += x1; x1 = rotl32(x1, 29); x1 ^= x0;
  x0 += x1; x1 = rotl32(x1, 16); x1 ^= x0;
  x0 += x1; x1 = rotl32(x1, 24); x1 ^= x0;
  x0 += ks2; x1 += k0 + 2u;
  x0 += x1; x1 = rotl32(x1, 13); x1 ^= x0;
  x0 += x1; x1 = rotl32(x1, 15); x1 ^= x0;
  x0 += x1; x1 = rotl32(x1, 26); x1 ^= x0;
  x0 += x1; x1 = rotl32(x1, 6);  x1 ^= x0;
  x0 += k0; x1 += k1 + 3u;
  x0 += x1; x1 = rotl32(x1, 17); x1 ^= x0;
  x0 += x1; x1 = rotl32(x1, 29); x1 ^= x0;
  x0 += x1; x1 = rotl32(x1, 16); x1 ^= x0;
  x0 += x1; x1 = rotl32(x1, 24); x1 ^= x0;
  x0 += k1; x1 += ks2 + 4u;
  x0 += x1; x1 = rotl32(x1, 13); x1 ^= x0;
  x0 += x1; x1 = rotl32(x1, 15); x1 ^= x0;
  x0 += x1; x1 = rotl32(x1, 26); x1 ^= x0;
  x0 += x1; x1 = rotl32(x1, 6);  x1 ^= x0;
  x0 += ks2; x1 += k0 + 5u;
  return TF2{x0, x1};
}

// In-quad butterfly adds on the VALU pipe (DPP quad_perm), replacing
// ds_bpermute-based __shfl_xor. Association identical: p += p(lane^1); then
// p += p(lane^2) -> all 4 lanes of a quad hold the quad sum.
__device__ __forceinline__ float dpp_xor1_add(float x) {
  int t = __builtin_amdgcn_mov_dpp(__float_as_int(x), 0xB1, 0xF, 0xF, true);  // quad_perm [1,0,3,2]
  return x + __int_as_float(t);
}
__device__ __forceinline__ float dpp_xor2_add(float x) {
  int t = __builtin_amdgcn_mov_dpp(__float_as_int(x), 0x4E, 0xF, 0xF, true);  // quad_perm [2,3,0,1]
  return x + __int_as_float(t);
}

// M[bh][q] = max_s dot(Q[q],K[idx[q][s]]) - sum_s(...)/4096.
// bh = blockIdx&15: with round-robin block->XCD dispatch, each XCD sees 2 bh
// -> 2 MB K slices stay L2-resident. idx computed inline (threefry).
__global__ __launch_bounds__(256) void k_scoreM(const float* __restrict__ Q, const float* __restrict__ K,
                                                float* __restrict__ M) {
  __shared__ float sp[720 * 5];    // [(qloc*45+s)*5 + g], g = subgroup 0..3
  __shared__ float ps[720];        // full dot per (qloc,s)
  __shared__ int sidx[720];
  int tid = threadIdx.x;
  int bx = blockIdx.x;
  int bh = bx & 15;
  int qblk = bx >> 4;              // 0..255
  int b = bh >> 3, h = bh & 7;
  int lane16 = tid & 15, qloc = tid >> 4;
  int q = qblk * 16 + qloc;
  constexpr TF2 kb = tf2(0u, 1u, 0u, 1u);
  for (int e = tid; e < 720; e += 256) {
    TF2 r = tf2(kb.a, kb.b, 0u, (unsigned)(qblk * 720 + e));
    sidx[e] = (int)((r.a ^ r.b) & 4095u);
  }
  __syncthreads();
  const vfloat4* Q4 = (const vfloat4*)Q;
  const vfloat4* K4 = (const vfloat4*)K;
  vfloat4 qr = Q4[((b * Lc + q) * Hc + h) * 16 + lane16];
  int kbase = (b * Lc * Hc + h) * 16 + lane16;
  const int* ip = sidx + qloc * NSc;
  float* wr = sp + (qloc * NSc) * 5 + (lane16 >> 2);
  bool wlane = (lane16 & 3) == 0;
  #pragma unroll
  for (int s0 = 0; s0 < NSc; s0 += 5) {      // 5-deep load batch: >=5 L2 loads in flight
    int kk[5];
    #pragma unroll
    for (int i = 0; i < 5; ++i) kk[i] = ip[s0 + i];
    vfloat4 kv[5];
    #pragma unroll
    for (int i = 0; i < 5; ++i) kv[i] = __builtin_nontemporal_load(&K4[kbase + kk[i] * (Hc * 16)]);
    #pragma unroll
    for (int i = 0; i < 5; ++i) {
      float p = qr[0] * kv[i][0] + qr[1] * kv[i][1] + qr[2] * kv[i][2] + qr[3] * kv[i][3];
      p = dpp_xor1_add(p);
      p = dpp_xor2_add(p);
      if (wlane) wr[(s0 + i) * 5] = p;
    }
  }
  __syncthreads();
  for (int p = tid; p < 720; p += 256) {
    const float* r = sp + p * 5;
    ps[p] = (r[0] + r[1]) + (r[2] + r[3]);
  }
  __syncthreads();
  if (tid < 16) {
    const float* r = ps + tid * NSc;
    float mx = r[0], sm = r[0];
    for (int s = 1; s < NSc; ++s) { float v = r[s]; mx = fmaxf(mx, v); sm += v; }
    M[bh * Lc + qblk * 16 + tid] = mx - sm * (1.0f / Lc);
  }
}

// Radix-select top-45 of 4096 per bh (exact lax.top_k: value desc, index asc
// on ties). Then pre-gather the 45 selected Q rows into qg[bh][45][64].
__global__ __launch_bounds__(256) void k_topk(const float* __restrict__ M, const float* __restrict__ Q,
                                              int* __restrict__ topk, float* __restrict__ qg) {
  __shared__ unsigned su[Lc];      // 16 KB mapped keys
  __shared__ int hist[256];
  __shared__ int sfx[257];
  __shared__ unsigned s_prefix;
  __shared__ int s_r;
  __shared__ int n_gt, n_eq;
  __shared__ unsigned cu[64];
  __shared__ int cidx[64];
  __shared__ int eqi[64];
  __shared__ int srank[Uc];
  int bh = blockIdx.x, tid = threadIdx.x;
  int b = bh >> 3, h = bh & 7;
  const float* m = M + bh * Lc;
  for (int e = tid; e < Lc; e += 256) {
    unsigned bb = __float_as_uint(m[e]);
    su[e] = (bb & 0x80000000u) ? ~bb : (bb | 0x80000000u);
  }
  if (tid == 0) { s_r = Uc; s_prefix = 0u; n_gt = 0; n_eq = 0; }
  __syncthreads();
  #pragma unroll
  for (int p = 0; p < 4; ++p) {
    int shift = 24 - 8 * p;
    hist[tid] = 0;
    __syncthreads();
    unsigned pref = s_prefix;
    unsigned hmask = (p == 0) ? 0u : (0xFFFFFFFFu << (shift + 8));
    for (int e = tid; e < Lc; e += 256) {
      unsigned u = su[e];
      if ((u & hmask) == pref) atomicAdd(&hist[(u >> shift) & 255u], 1);
    }
    __syncthreads();
    sfx[tid] = hist[tid];
    __syncthreads();
    for (int off = 1; off < 256; off <<= 1) {   // inclusive suffix sum
      int v = (tid + off < 256) ? sfx[tid + off] : 0;
      __syncthreads();
      sfx[tid] += v;
      __syncthreads();
    }
    int r = s_r;
    __syncthreads();                            // all read s_r before update
    int above = (tid < 255) ? sfx[tid + 1] : 0;
    if (sfx[tid] >= r && above < r) {           // unique digit
      s_r = r - above;
      s_prefix = pref | ((unsigned)tid << shift);
    }
    __syncthreads();
  }
  unsigned T = s_prefix;                        // exact 45th-largest key
  int rf = s_r;                                 // #equals to take (>=1)
  for (int e = tid; e < Lc; e += 256) {
    unsigned u = su[e];
    if (u > T) {
      int p = atomicAdd(&n_gt, 1);              // <= 44
      cu[p] = u; cidx[p] = e;
    } else if (u == T) {
      int p = atomicAdd(&n_eq, 1);
      if (p < 64) eqi[p] = e;                   // >64-way ties: impossible for random-normal M
    }
  }
  __syncthreads();
  int ne = n_eq < 64 ? n_eq : 64;
  if (tid < ne) {
    int myi = eqi[tid];
    int rank = 0;
    for (int j = 0; j < ne; ++j) rank += (eqi[j] < myi);
    if (rank < rf) {
      int p = atomicAdd(&n_gt, 1);              // completes to exactly 45
      cu[p] = T; cidx[p] = myi;
    }
  }
  __syncthreads();
  if (tid < Uc) {
    unsigned mu = cu[tid]; int mi = cidx[tid];
    int rank = 0;
    for (int j = 0; j < Uc; ++j) {
      unsigned ju = cu[j]; int ji = cidx[j];
      rank += (ju > mu) || (ju == mu && ji < mi);
    }
    topk[bh * Uc + rank] = mi;
    srank[rank] = mi;
  }
  __syncthreads();
  const float4* Q4 = (const float4*)Q;
  float4* qg4 = (float4*)qg;
  for (int e = tid; e < Uc * 16; e += 256) {    // coalesced pre-gather of selected Q rows
    int t = e >> 4, dq = e & 15;
    qg4[bh * Uc * 16 + e] = Q4[((b * Lc + srank[t]) * Hc + h) * 16 + dq];
  }
}

// Flash-decoding partials: one block per (bh, CH-key chunk), CH = 4096/NC.
template<int NC>
__global__ __launch_bounds__(256) void k_attn(const float* __restrict__ qg, const float* __restrict__ K,
                                              const float* __restrict__ V, const int* __restrict__ amask,
                                              float* __restrict__ pO, float* __restrict__ pM,
                                              float* __restrict__ pL) {
  constexpr int CH = Lc / NC;
  constexpr int TG = 256 / CH;
  int chunk = blockIdx.x, bh = blockIdx.y;
  int b = bh >> 3, h = bh & 7;
  int tid = threadIdx.x;
  __shared__ __align__(16) float qs[Uc * 64];
  __shared__ float sc[48][CH + 1];
  {
    const float4* qg4 = (const float4*)qg;
    float4* qs4w = (float4*)qs;
    for (int e = tid; e < Uc * 16; e += 256) qs4w[e] = qg4[bh * Uc * 16 + e];
  }
  for (int e = tid; e < 3 * CH; e += 256) sc[45 + e / CH][e % CH] = 0.f;
  __syncthreads();
  {
    int k = tid % CH, tg = tid / CH;
    int key = chunk * CH + k;
    const float4* K4 = (const float4*)K;
    int kb = ((b * Lc + key) * Hc + h) * 16;
    float4 kr[16];
    #pragma unroll
    for (int j = 0; j < 16; ++j) kr[j] = K4[kb + j];
    int mk = amask[b * Lc + key];
    const float4* qs4 = (const float4*)qs;
    for (int t = tg; t < Uc; t += TG) {
      float acc = 0.f;
      #pragma unroll
      for (int j = 0; j < 16; ++j) {
        float4 qv = qs4[t * 16 + j];
        acc += qv.x * kr[j].x;
        acc += qv.y * kr[j].y;
        acc += qv.z * kr[j].z;
        acc += qv.w * kr[j].w;
      }
      sc[t][k] = mk ? acc * 0.125f : -INFINITY;
    }
  }
  __syncthreads();
  {
    constexpr int COLS = CH / 64;
    int w = tid >> 6, lane = tid & 63;
    for (int t = w; t < Uc; t += 4) {
      float x[COLS];
      float ml = -INFINITY;
      #pragma unroll
      for (int c = 0; c < COLS; ++c) { x[c] = sc[t][c * 64 + lane]; ml = fmaxf(ml, x[c]); }
      #pragma unroll
      for (int off = 1; off < 64; off <<= 1) ml = fmaxf(ml, __shfl_xor(ml, off));
      float ls = 0.f;
      if (ml != -INFINITY) {
        #pragma unroll
        for (int c = 0; c < COLS; ++c) { x[c] = __expf(x[c] - ml); ls += x[c]; }
      } else {
        #pragma unroll
        for (int c = 0; c < COLS; ++c) x[c] = 0.f;
      }
      #pragma unroll
      for (int c = 0; c < COLS; ++c) sc[t][c * 64 + lane] = x[c];
      #pragma unroll
      for (int off = 1; off < 64; off <<= 1) ls += __shfl_xor(ls, off);
      if (lane == 0) {
        pM[(bh * NC + chunk) * Uc + t] = ml;
        pL[(bh * NC + chunk) * Uc + t] = ls;
      }
    }
  }
  __syncthreads();
  {
    int ty = tid >> 4, tx = tid & 15;
    float4 o0 = {0.f, 0.f, 0.f, 0.f};
    float4 o1 = {0.f, 0.f, 0.f, 0.f};
    float4 o2 = {0.f, 0.f, 0.f, 0.f};
    const float4* V4 = (const float4*)V;
    int vbase = (b * Lc + chunk * CH) * (Hc * 16) + h * 16 + tx;
    #pragma unroll 4
    for (int k = 0; k < CH; ++k) {
      float4 v4 = V4[vbase + k * (Hc * 16)];
      float p0 = sc[ty][k], p1 = sc[ty + 16][k], p2 = sc[ty + 32][k];
      o0.x += p0 * v4.x; o0.y += p0 * v4.y; o0.z += p0 * v4.z; o0.w += p0 * v4.w;
      o1.x += p1 * v4.x; o1.y += p1 * v4.y; o1.z += p1 * v4.z; o1.w += p1 * v4.w;
      o2.x += p2 * v4.x; o2.y += p2 * v4.y; o2.z += p2 * v4.z; o2.w += p2 * v4.w;
    }
    float4* pO4 = (float4*)pO;
    int obase = ((bh * NC + chunk) * Uc) * 16 + tx;
    pO4[obase + ty * 16] = o0;
    pO4[obase + (ty + 16) * 16] = o1;
    if (ty < 13) pO4[obase + (ty + 32) * 16] = o2;
  }
}

// Exact merge of chunk partials; out[b][t][h][d].
template<int NC>
__global__ __launch_bounds__(256) void k_merge(const float* __restrict__ pO, const float* __restrict__ pM,
                                               const float* __restrict__ pL, float* __restrict__ out) {
  int f = blockIdx.x * 256 + threadIdx.x;   // 180*256 == 46080
  int d = f & 63, h = (f >> 6) & 7;
  int bt = f >> 9;
  int t = bt % Uc, b = bt / Uc;
  int bh = b * 8 + h;
  float m = -INFINITY;
  for (int c = 0; c < NC; ++c) m = fmaxf(m, pM[(bh * NC + c) * Uc + t]);
  float den = 0.f, num = 0.f;
  for (int c = 0; c < NC; ++c) {
    float mc = pM[(bh * NC + c) * Uc + t];
    float wgt = (mc == -INFINITY) ? 0.f : __expf(mc - m);
    den += wgt * pL[(bh * NC + c) * Uc + t];
    num += wgt * pO[((bh * NC + c) * Uc + t) * 64 + d];
  }
  out[f] = num / den;
}

extern "C" void kernel_launch(void* const* d_in, const int* in_sizes, int n_in,
                              void* d_out, int out_size, void* d_ws, size_t ws_size,
                              hipStream_t stream) {
  const float* Q = (const float*)d_in[0];
  const float* K = (const float*)d_in[1];
  const float* V = (const float*)d_in[2];
  const int* amask = (const int*)d_in[3];
  float* out = (float*)d_out;
  char* ws = (char*)d_ws;
  float* M    = (float*)(ws + 0x000000);   // 65536 floats (256 KB)
  int*   topk = (int*)(ws + 0x040000);     // 720 ints
  float* qg   = (float*)(ws + 0x041000);   // 16*45*64 floats (184,320 B)
  float* pM   = (float*)(ws + 0x070000);
  // ws_size is constant across calls -> branch is deterministic (graph-safe).
  size_t need64 = 0x70000UL + 64UL * 190080UL;   // pM+pL+pO for NC=64 (~12.6 MB)
  size_t need32 = 0x70000UL + 32UL * 190080UL;
  int NC = ws_size >= need64 ? 64 : (ws_size >= need32 ? 32 : 16);
  float* pL = pM + 16 * NC * Uc;
  float* pO = pL + 16 * NC * Uc;

  k_scoreM<<<4096, 256, 0, stream>>>(Q, K, M);
  k_topk<<<BHc, 256, 0, stream>>>(M, Q, topk, qg);
  if (NC == 64) {
    k_attn<64><<<dim3(64, BHc), 256, 0, stream>>>(qg, K, V, amask, pO, pM, pL);
    k_merge<64><<<180, 256, 0, stream>>>(pO, pM, pL, out);
  } else if (NC == 32) {
    k_attn<32><<<dim3(32, BHc), 256, 0, stream>>>(qg, K, V, amask, pO, pM, pL);
    k_merge<32><<<180, 256, 0, stream>>>(pO, pM, pL, out);
  } else {
    k_attn<16><<<dim3(16, BHc), 256, 0, stream>>>(qg, K, V, amask, pO, pM, pL);
    k_merge<16><<<180, 256, 0, stream>>>(pO, pM, pL, out);
  }
}

// Round 7
// 181.519 us; speedup vs baseline: 1.3477x; 1.0055x over previous
//
#include <hip/hip_runtime.h>
#include <math.h>

// ProbSparse attention (Informer). B=2 L=4096 H=8 D=64, U_part=u=45.
// R6: k_scoreM keeps running max/sum in registers. Per (q,s): 4-FMA dot
// partial -> DPP row_shr cascade (1,2,4,8; balanced tree == R1's butterfly
// up to commutativity) -> lane15 holds full dot -> sequential max/sum.
// No sp/ps LDS round-trip, 1 barrier instead of 3, LDS 20.5KB -> ~3KB.
#define JAX_PARTITIONABLE 1

constexpr int Bc = 2, Lc = 4096, Hc = 8, Dc = 64;
constexpr int BHc = Bc * Hc;     // 16
constexpr int Uc = 45;           // top-k queries
constexpr int NSc = 45;          // samples per query

typedef float vfloat4 __attribute__((ext_vector_type(4)));

struct TF2 { unsigned a, b; };

__host__ __device__ constexpr unsigned rotl32(unsigned v, int n) {
  return (v << n) | (v >> (32 - n));
}

// Threefry-2x32, 20 rounds (JAX reference schedule).
__host__ __device__ constexpr TF2 tf2(unsigned k0, unsigned k1, unsigned x0, unsigned x1) {
  unsigned ks2 = k0 ^ k1 ^ 0x1BD11BDAu;
  x0 += k0; x1 += k1;
  x0 += x1; x1 = rotl32(x1, 13); x1 ^= x0;
  x0 += x1; x1 = rotl32(x1, 15); x1 ^= x0;
  x0 += x1; x1 = rotl32(x1, 26); x1 ^= x0;
  x0 += x1; x1 = rotl32(x1, 6);  x1 ^= x0;
  x0 += k1; x1 += ks2 + 1u;
  x0 += x1; x1 = rotl32(x1, 17); x1 ^= x0;
  x0 += x1; x1 = rotl32(x1, 29); x1 ^= x0;
  x0 += x1; x1 = rotl32(x1, 16); x1 ^= x0;
  x0 += x1; x1 = rotl32(x1, 24); x1 ^= x0;
  x0 += ks2; x1 += k0 + 2u;
  x0 += x1; x1 = rotl32(x1, 13); x1 ^= x0;
  x0 += x1; x1 = rotl32(x1, 15); x1 ^= x0;
  x0 += x1; x1 = rotl32(x1, 26); x1 ^= x0;
  x0 += x1; x1 = rotl32(x1, 6);  x1 ^= x0;
  x0 += k0; x1 += k1 + 3u;
  x0 += x1; x1 = rotl32(x1, 17); x1 ^= x0;
  x0 += x1; x1 = rotl32(x1, 29); x1 ^= x0;
  x0 += x1; x1 = rotl32(x1, 16); x1 ^= x0;
  x0 += x1; x1 = rotl32(x1, 24); x1 ^= x0;
  x0 += k1; x1 += ks2 + 4u;
  x0 += x1; x1 = rotl32(x1, 13); x1 ^= x0;
  x0 += x1; x1 = rotl32(x1, 15); x1 ^= x0;
  x0 += x1; x1 = rotl32(x1, 26); x1 ^= x0;
  x0 += x1; x1 = rotl32(x1, 6);  x1 ^= x0;
  x0 += ks2; x1 += k0 + 5u;
  return TF2{x0, x1};
}

// VALU-pipe partial-sum add via DPP. CTRL: row_shr:N = 0x110+N.
// bound_ctrl=true => out-of-row source reads 0 (identity for add).
template <int CTRL>
__device__ __forceinline__ float dpp_add(float x) {
  int t = __builtin_amdgcn_mov_dpp(__float_as_int(x), CTRL, 0xF, 0xF, true);
  return x + __int_as_float(t);
}

// M[bh][q] = max_s dot(Q[q],K[idx[q][s]]) - sum_s(...)/4096.
// bh = blockIdx&15: with round-robin block->XCD dispatch, each XCD sees 2 bh
// -> 2 MB K slices stay L2-resident. idx computed inline (threefry).
// Row group (16 lanes) owns one q; running max/sum live at lane15.
__global__ __launch_bounds__(256) void k_scoreM(const float* __restrict__ Q, const float* __restrict__ K,
                                                float* __restrict__ M) {
  __shared__ int sidx[720];
  int tid = threadIdx.x;
  int bx = blockIdx.x;
  int bh = bx & 15;
  int qblk = bx >> 4;              // 0..255
  int b = bh >> 3, h = bh & 7;
  int lane16 = tid & 15, qloc = tid >> 4;
  int q = qblk * 16 + qloc;
  constexpr TF2 kb = tf2(0u, 1u, 0u, 1u);
  for (int e = tid; e < 720; e += 256) {
    TF2 r = tf2(kb.a, kb.b, 0u, (unsigned)(qblk * 720 + e));
    sidx[e] = (int)((r.a ^ r.b) & 4095u);
  }
  __syncthreads();
  const vfloat4* Q4 = (const vfloat4*)Q;
  const vfloat4* K4 = (const vfloat4*)K;
  vfloat4 qr = Q4[((b * Lc + q) * Hc + h) * 16 + lane16];
  int kbase = (b * Lc * Hc + h) * 16 + lane16;
  const int* ip = sidx + qloc * NSc;
  float mx = -INFINITY, sm = 0.f;
  #pragma unroll
  for (int s0 = 0; s0 < NSc; s0 += 5) {      // 5-deep load batch: L2 loads in flight
    int kk[5];
    #pragma unroll
    for (int i = 0; i < 5; ++i) kk[i] = ip[s0 + i];
    vfloat4 kv[5];
    #pragma unroll
    for (int i = 0; i < 5; ++i) kv[i] = __builtin_nontemporal_load(&K4[kbase + kk[i] * (Hc * 16)]);
    #pragma unroll
    for (int i = 0; i < 5; ++i) {
      float p = qr[0] * kv[i][0] + qr[1] * kv[i][1] + qr[2] * kv[i][2] + qr[3] * kv[i][3];
      p = dpp_add<0x111>(p);                 // row_shr:1
      p = dpp_add<0x112>(p);                 // row_shr:2
      p = dpp_add<0x114>(p);                 // row_shr:4
      p = dpp_add<0x118>(p);                 // row_shr:8 -> lane15 = full dot
      mx = fmaxf(mx, p);                     // valid at lane15; junk elsewhere (never read)
      sm += p;
    }
  }
  if (lane16 == 15) M[bh * Lc + q] = mx - sm * (1.0f / Lc);
}

// Radix-select top-45 of 4096 per bh (exact lax.top_k: value desc, index asc
// on ties). Then pre-gather the 45 selected Q rows into qg[bh][45][64].
__global__ __launch_bounds__(256) void k_topk(const float* __restrict__ M, const float* __restrict__ Q,
                                              int* __restrict__ topk, float* __restrict__ qg) {
  __shared__ unsigned su[Lc];      // 16 KB mapped keys
  __shared__ int hist[256];
  __shared__ int sfx[257];
  __shared__ unsigned s_prefix;
  __shared__ int s_r;
  __shared__ int n_gt, n_eq;
  __shared__ unsigned cu[64];
  __shared__ int cidx[64];
  __shared__ int eqi[64];
  __shared__ int srank[Uc];
  int bh = blockIdx.x, tid = threadIdx.x;
  int b = bh >> 3, h = bh & 7;
  const float* m = M + bh * Lc;
  for (int e = tid; e < Lc; e += 256) {
    unsigned bb = __float_as_uint(m[e]);
    su[e] = (bb & 0x80000000u) ? ~bb : (bb | 0x80000000u);
  }
  if (tid == 0) { s_r = Uc; s_prefix = 0u; n_gt = 0; n_eq = 0; }
  __syncthreads();
  #pragma unroll
  for (int p = 0; p < 4; ++p) {
    int shift = 24 - 8 * p;
    hist[tid] = 0;
    __syncthreads();
    unsigned pref = s_prefix;
    unsigned hmask = (p == 0) ? 0u : (0xFFFFFFFFu << (shift + 8));
    for (int e = tid; e < Lc; e += 256) {
      unsigned u = su[e];
      if ((u & hmask) == pref) atomicAdd(&hist[(u >> shift) & 255u], 1);
    }
    __syncthreads();
    sfx[tid] = hist[tid];
    __syncthreads();
    for (int off = 1; off < 256; off <<= 1) {   // inclusive suffix sum
      int v = (tid + off < 256) ? sfx[tid + off] : 0;
      __syncthreads();
      sfx[tid] += v;
      __syncthreads();
    }
    int r = s_r;
    __syncthreads();                            // all read s_r before update
    int above = (tid < 255) ? sfx[tid + 1] : 0;
    if (sfx[tid] >= r && above < r) {           // unique digit
      s_r = r - above;
      s_prefix = pref | ((unsigned)tid << shift);
    }
    __syncthreads();
  }
  unsigned T = s_prefix;                        // exact 45th-largest key
  int rf = s_r;                                 // #equals to take (>=1)
  for (int e = tid; e < Lc; e += 256) {
    unsigned u = su[e];
    if (u > T) {
      int p = atomicAdd(&n_gt, 1);              // <= 44
      cu[p] = u; cidx[p] = e;
    } else if (u == T) {
      int p = atomicAdd(&n_eq, 1);
      if (p < 64) eqi[p] = e;                   // >64-way ties: impossible for random-normal M
    }
  }
  __syncthreads();
  int ne = n_eq < 64 ? n_eq : 64;
  if (tid < ne) {
    int myi = eqi[tid];
    int rank = 0;
    for (int j = 0; j < ne; ++j) rank += (eqi[j] < myi);
    if (rank < rf) {
      int p = atomicAdd(&n_gt, 1);              // completes to exactly 45
      cu[p] = T; cidx[p] = myi;
    }
  }
  __syncthreads();
  if (tid < Uc) {
    unsigned mu = cu[tid]; int mi = cidx[tid];
    int rank = 0;
    for (int j = 0; j < Uc; ++j) {
      unsigned ju = cu[j]; int ji = cidx[j];
      rank += (ju > mu) || (ju == mu && ji < mi);
    }
    topk[bh * Uc + rank] = mi;
    srank[rank] = mi;
  }
  __syncthreads();
  const float4* Q4 = (const float4*)Q;
  float4* qg4 = (float4*)qg;
  for (int e = tid; e < Uc * 16; e += 256) {    // coalesced pre-gather of selected Q rows
    int t = e >> 4, dq = e & 15;
    qg4[bh * Uc * 16 + e] = Q4[((b * Lc + srank[t]) * Hc + h) * 16 + dq];
  }
}

// Flash-decoding partials: one block per (bh, CH-key chunk), CH = 4096/NC.
template<int NC>
__global__ __launch_bounds__(256) void k_attn(const float* __restrict__ qg, const float* __restrict__ K,
                                              const float* __restrict__ V, const int* __restrict__ amask,
                                              float* __restrict__ pO, float* __restrict__ pM,
                                              float* __restrict__ pL) {
  constexpr int CH = Lc / NC;
  constexpr int TG = 256 / CH;
  int chunk = blockIdx.x, bh = blockIdx.y;
  int b = bh >> 3, h = bh & 7;
  int tid = threadIdx.x;
  __shared__ __align__(16) float qs[Uc * 64];
  __shared__ float sc[48][CH + 1];
  {
    const float4* qg4 = (const float4*)qg;
    float4* qs4w = (float4*)qs;
    for (int e = tid; e < Uc * 16; e += 256) qs4w[e] = qg4[bh * Uc * 16 + e];
  }
  for (int e = tid; e < 3 * CH; e += 256) sc[45 + e / CH][e % CH] = 0.f;
  __syncthreads();
  {
    int k = tid % CH, tg = tid / CH;
    int key = chunk * CH + k;
    const float4* K4 = (const float4*)K;
    int kb = ((b * Lc + key) * Hc + h) * 16;
    float4 kr[16];
    #pragma unroll
    for (int j = 0; j < 16; ++j) kr[j] = K4[kb + j];
    int mk = amask[b * Lc + key];
    const float4* qs4 = (const float4*)qs;
    for (int t = tg; t < Uc; t += TG) {
      float acc = 0.f;
      #pragma unroll
      for (int j = 0; j < 16; ++j) {
        float4 qv = qs4[t * 16 + j];
        acc += qv.x * kr[j].x;
        acc += qv.y * kr[j].y;
        acc += qv.z * kr[j].z;
        acc += qv.w * kr[j].w;
      }
      sc[t][k] = mk ? acc * 0.125f : -INFINITY;
    }
  }
  __syncthreads();
  {
    constexpr int COLS = CH / 64;
    int w = tid >> 6, lane = tid & 63;
    for (int t = w; t < Uc; t += 4) {
      float x[COLS];
      float ml = -INFINITY;
      #pragma unroll
      for (int c = 0; c < COLS; ++c) { x[c] = sc[t][c * 64 + lane]; ml = fmaxf(ml, x[c]); }
      #pragma unroll
      for (int off = 1; off < 64; off <<= 1) ml = fmaxf(ml, __shfl_xor(ml, off));
      float ls = 0.f;
      if (ml != -INFINITY) {
        #pragma unroll
        for (int c = 0; c < COLS; ++c) { x[c] = __expf(x[c] - ml); ls += x[c]; }
      } else {
        #pragma unroll
        for (int c = 0; c < COLS; ++c) x[c] = 0.f;
      }
      #pragma unroll
      for (int c = 0; c < COLS; ++c) sc[t][c * 64 + lane] = x[c];
      #pragma unroll
      for (int off = 1; off < 64; off <<= 1) ls += __shfl_xor(ls, off);
      if (lane == 0) {
        pM[(bh * NC + chunk) * Uc + t] = ml;
        pL[(bh * NC + chunk) * Uc + t] = ls;
      }
    }
  }
  __syncthreads();
  {
    int ty = tid >> 4, tx = tid & 15;
    float4 o0 = {0.f, 0.f, 0.f, 0.f};
    float4 o1 = {0.f, 0.f, 0.f, 0.f};
    float4 o2 = {0.f, 0.f, 0.f, 0.f};
    const float4* V4 = (const float4*)V;
    int vbase = (b * Lc + chunk * CH) * (Hc * 16) + h * 16 + tx;
    #pragma unroll 4
    for (int k = 0; k < CH; ++k) {
      float4 v4 = V4[vbase + k * (Hc * 16)];
      float p0 = sc[ty][k], p1 = sc[ty + 16][k], p2 = sc[ty + 32][k];
      o0.x += p0 * v4.x; o0.y += p0 * v4.y; o0.z += p0 * v4.z; o0.w += p0 * v4.w;
      o1.x += p1 * v4.x; o1.y += p1 * v4.y; o1.z += p1 * v4.z; o1.w += p1 * v4.w;
      o2.x += p2 * v4.x; o2.y += p2 * v4.y; o2.z += p2 * v4.z; o2.w += p2 * v4.w;
    }
    float4* pO4 = (float4*)pO;
    int obase = ((bh * NC + chunk) * Uc) * 16 + tx;
    pO4[obase + ty * 16] = o0;
    pO4[obase + (ty + 16) * 16] = o1;
    if (ty < 13) pO4[obase + (ty + 32) * 16] = o2;
  }
}

// Exact merge of chunk partials; out[b][t][h][d].
template<int NC>
__global__ __launch_bounds__(256) void k_merge(const float* __restrict__ pO, const float* __restrict__ pM,
                                               const float* __restrict__ pL, float* __restrict__ out) {
  int f = blockIdx.x * 256 + threadIdx.x;   // 180*256 == 46080
  int d = f & 63, h = (f >> 6) & 7;
  int bt = f >> 9;
  int t = bt % Uc, b = bt / Uc;
  int bh = b * 8 + h;
  float m = -INFINITY;
  for (int c = 0; c < NC; ++c) m = fmaxf(m, pM[(bh * NC + c) * Uc + t]);
  float den = 0.f, num = 0.f;
  for (int c = 0; c < NC; ++c) {
    float mc = pM[(bh * NC + c) * Uc + t];
    float wgt = (mc == -INFINITY) ? 0.f : __expf(mc - m);
    den += wgt * pL[(bh * NC + c) * Uc + t];
    num += wgt * pO[((bh * NC + c) * Uc + t) * 64 + d];
  }
  out[f] = num / den;
}

extern "C" void kernel_launch(void* const* d_in, const int* in_sizes, int n_in,
                              void* d_out, int out_size, void* d_ws, size_t ws_size,
                              hipStream_t stream) {
  const float* Q = (const float*)d_in[0];
  const float* K = (const float*)d_in[1];
  const float* V = (const float*)d_in[2];
  const int* amask = (const int*)d_in[3];
  float* out = (float*)d_out;
  char* ws = (char*)d_ws;
  float* M    = (float*)(ws + 0x000000);   // 65536 floats (256 KB)
  int*   topk = (int*)(ws + 0x040000);     // 720 ints
  float* qg   = (float*)(ws + 0x041000);   // 16*45*64 floats (184,320 B)
  float* pM   = (float*)(ws + 0x070000);
  // ws_size is constant across calls -> branch is deterministic (graph-safe).
  size_t need64 = 0x70000UL + 64UL * 190080UL;   // pM+pL+pO for NC=64 (~12.6 MB)
  size_t need32 = 0x70000UL + 32UL * 190080UL;
  int NC = ws_size >= need64 ? 64 : (ws_size >= need32 ? 32 : 16);
  float* pL = pM + 16 * NC * Uc;
  float* pO = pL + 16 * NC * Uc;

  k_scoreM<<<4096, 256, 0, stream>>>(Q, K, M);
  k_topk<<<BHc, 256, 0, stream>>>(M, Q, topk, qg);
  if (NC == 64) {
    k_attn<64><<<dim3(64, BHc), 256, 0, stream>>>(qg, K, V, amask, pO, pM, pL);
    k_merge<64><<<180, 256, 0, stream>>>(pO, pM, pL, out);
  } else if (NC == 32) {
    k_attn<32><<<dim3(32, BHc), 256, 0, stream>>>(qg, K, V, amask, pO, pM, pL);
    k_merge<32><<<180, 256, 0, stream>>>(pO, pM, pL, out);
  } else {
    k_attn<16><<<dim3(16, BHc), 256, 0, stream>>>(qg, K, V, amask, pO, pM, pL);
    k_merge<16><<<180, 256, 0, stream>>>(pO, pM, pL, out);
  }
}